// Round 2
// baseline (2358.466 us; speedup 1.0000x reference)
//
#include <hip/hip_runtime.h>
#include <math.h>
#include <type_traits>

// ---------------------------------------------------------------------------
// VQ-VAE forward: recon, z_e, emb_o
//   h1   = relu(x @ W1^T + b1)            (16384, 400)   [fp64 accum]
//   z_e  = h1 @ W2^T + b2                 (16384, 1024)  [fp64 accum; f32 out + f32 residual]
//   z_q  = nearest-codebook(z_e)          (16384, 1024)  [fp64 distances -> exact argmin]
//   h3   = relu(z_q @ W3^T + b3)          (16384, 400)   [fp32]
//   recon= sigmoid(h3 @ W4^T + b4)        (16384, 3072)  [fp32]
// Rationale: harness ref is near-exact (np/f64). A single argmin flip costs
// ~0.027 absmax on recon (> 0.02 threshold) — so the entire encoder+distance
// path must be near-exact. Decoder tolerance is loose; fp32 suffices.
// ---------------------------------------------------------------------------

#define TILE 128
#define BK   16
#define LP   132   // LDS pitch: breaks transpose-write bank conflicts

// ============================ fp32 GEMM (decoder) ===========================
// C[M,N] = act(A[M,K] @ W[N,K]^T + bias). ACT: 0 none, 1 relu, 2 sigmoid
template<int ACT>
__global__ __launch_bounds__(256) void gemm_f32(
    const float* __restrict__ A, const float* __restrict__ W,
    const float* __restrict__ bias, float* __restrict__ C,
    int M, int N, int K)
{
    __shared__ float As[BK * LP];
    __shared__ float Ws[BK * LP];

    const int tid = threadIdx.x;
    const int tx = tid & 15;
    const int ty = tid >> 4;
    const int m0 = blockIdx.y * TILE;
    const int n0 = blockIdx.x * TILE;

    float acc[8][8];
    #pragma unroll
    for (int i = 0; i < 8; ++i)
        #pragma unroll
        for (int j = 0; j < 8; ++j) acc[i][j] = 0.f;

    for (int kt = 0; kt < K; kt += BK) {
        #pragma unroll
        for (int it = 0; it < 2; ++it) {
            const int f   = tid + it * 256;
            const int row = f >> 2;
            const int c4  = (f & 3) << 2;

            float4 va = *reinterpret_cast<const float4*>(
                &A[(size_t)(m0 + row) * K + kt + c4]);
            As[(c4 + 0) * LP + row] = va.x;
            As[(c4 + 1) * LP + row] = va.y;
            As[(c4 + 2) * LP + row] = va.z;
            As[(c4 + 3) * LP + row] = va.w;

            const int n = n0 + row;
            float4 vw = make_float4(0.f, 0.f, 0.f, 0.f);
            if (n < N)
                vw = *reinterpret_cast<const float4*>(
                    &W[(size_t)n * K + kt + c4]);
            Ws[(c4 + 0) * LP + row] = vw.x;
            Ws[(c4 + 1) * LP + row] = vw.y;
            Ws[(c4 + 2) * LP + row] = vw.z;
            Ws[(c4 + 3) * LP + row] = vw.w;
        }
        __syncthreads();

        #pragma unroll
        for (int k = 0; k < BK; ++k) {
            const float4 A0 = *reinterpret_cast<const float4*>(&As[k * LP + ty * 4]);
            const float4 A1 = *reinterpret_cast<const float4*>(&As[k * LP + 64 + ty * 4]);
            const float4 B0 = *reinterpret_cast<const float4*>(&Ws[k * LP + tx * 4]);
            const float4 B1 = *reinterpret_cast<const float4*>(&Ws[k * LP + 64 + tx * 4]);
            const float a[8] = {A0.x, A0.y, A0.z, A0.w, A1.x, A1.y, A1.z, A1.w};
            const float b[8] = {B0.x, B0.y, B0.z, B0.w, B1.x, B1.y, B1.z, B1.w};
            #pragma unroll
            for (int i = 0; i < 8; ++i)
                #pragma unroll
                for (int j = 0; j < 8; ++j)
                    acc[i][j] = fmaf(a[i], b[j], acc[i][j]);
        }
        __syncthreads();
    }

    float bv[8];
    #pragma unroll
    for (int jb = 0; jb < 2; ++jb)
        #pragma unroll
        for (int j = 0; j < 4; ++j) {
            const int n = n0 + jb * 64 + tx * 4 + j;
            bv[jb * 4 + j] = (n < N) ? bias[n] : 0.f;
        }

    #pragma unroll
    for (int ib = 0; ib < 2; ++ib)
        #pragma unroll
        for (int i = 0; i < 4; ++i) {
            const int m = m0 + ib * 64 + ty * 4 + i;
            #pragma unroll
            for (int jb = 0; jb < 2; ++jb) {
                const int n = n0 + jb * 64 + tx * 4;
                if (n < N) {
                    float4 o;
                    float* oc = reinterpret_cast<float*>(&o);
                    #pragma unroll
                    for (int j = 0; j < 4; ++j) {
                        float v = acc[ib * 4 + i][jb * 4 + j] + bv[jb * 4 + j];
                        if (ACT == 1) v = fmaxf(v, 0.f);
                        else if (ACT == 2) v = 1.f / (1.f + expf(-v));
                        oc[j] = v;
                    }
                    *reinterpret_cast<float4*>(&C[(size_t)m * N + n]) = o;
                }
            }
        }
}

// ===================== fp64-accumulate GEMM (encoder) =======================
// A: TA (float or double) row-major MxK; W: f32 NxK; C: TC (float or double).
// If Res != null (requires TC=float): Res[m,n] = f32 residual of f64 result,
// so (double)C + (double)Res reconstructs the f64 value to ~2^-48 rel.
template<int ACT, typename TA, typename TC>
__global__ __launch_bounds__(256) void gemm_f64acc(
    const TA* __restrict__ A, const float* __restrict__ W,
    const float* __restrict__ bias, TC* __restrict__ C,
    float* __restrict__ Res, int M, int N, int K)
{
    __shared__ double As[BK * LP];   // 16.9 KB
    __shared__ double Ws[BK * LP];   // 16.9 KB

    const int tid = threadIdx.x;
    const int tx = tid & 15;
    const int ty = tid >> 4;
    const int m0 = blockIdx.y * TILE;
    const int n0 = blockIdx.x * TILE;

    double acc[8][8];
    #pragma unroll
    for (int i = 0; i < 8; ++i)
        #pragma unroll
        for (int j = 0; j < 8; ++j) acc[i][j] = 0.0;

    for (int kt = 0; kt < K; kt += BK) {
        // ---- stage A (convert to f64 in LDS, transposed) ----
        if constexpr (std::is_same<TA, float>::value) {
            #pragma unroll
            for (int it = 0; it < 2; ++it) {
                const int f   = tid + it * 256;
                const int row = f >> 2;
                const int c4  = (f & 3) << 2;
                float4 va = *reinterpret_cast<const float4*>(
                    &A[(size_t)(m0 + row) * K + kt + c4]);
                As[(c4 + 0) * LP + row] = (double)va.x;
                As[(c4 + 1) * LP + row] = (double)va.y;
                As[(c4 + 2) * LP + row] = (double)va.z;
                As[(c4 + 3) * LP + row] = (double)va.w;
            }
        } else {
            #pragma unroll
            for (int it = 0; it < 4; ++it) {
                const int f   = tid + it * 256;      // 0..1023
                const int row = f >> 3;              // 0..127
                const int c2  = (f & 7) << 1;        // 0,2,..,14
                double2 va = *reinterpret_cast<const double2*>(
                    &A[(size_t)(m0 + row) * K + kt + c2]);
                As[(c2 + 0) * LP + row] = va.x;
                As[(c2 + 1) * LP + row] = va.y;
            }
        }
        // ---- stage W (f32 -> f64, transposed, N-guarded) ----
        #pragma unroll
        for (int it = 0; it < 2; ++it) {
            const int f   = tid + it * 256;
            const int row = f >> 2;
            const int c4  = (f & 3) << 2;
            const int n = n0 + row;
            float4 vw = make_float4(0.f, 0.f, 0.f, 0.f);
            if (n < N)
                vw = *reinterpret_cast<const float4*>(
                    &W[(size_t)n * K + kt + c4]);
            Ws[(c4 + 0) * LP + row] = (double)vw.x;
            Ws[(c4 + 1) * LP + row] = (double)vw.y;
            Ws[(c4 + 2) * LP + row] = (double)vw.z;
            Ws[(c4 + 3) * LP + row] = (double)vw.w;
        }
        __syncthreads();

        #pragma unroll
        for (int k = 0; k < BK; ++k) {
            const double2 A0 = *reinterpret_cast<const double2*>(&As[k * LP + ty * 4]);
            const double2 A1 = *reinterpret_cast<const double2*>(&As[k * LP + ty * 4 + 2]);
            const double2 A2 = *reinterpret_cast<const double2*>(&As[k * LP + 64 + ty * 4]);
            const double2 A3 = *reinterpret_cast<const double2*>(&As[k * LP + 64 + ty * 4 + 2]);
            const double2 B0 = *reinterpret_cast<const double2*>(&Ws[k * LP + tx * 4]);
            const double2 B1 = *reinterpret_cast<const double2*>(&Ws[k * LP + tx * 4 + 2]);
            const double2 B2 = *reinterpret_cast<const double2*>(&Ws[k * LP + 64 + tx * 4]);
            const double2 B3 = *reinterpret_cast<const double2*>(&Ws[k * LP + 64 + tx * 4 + 2]);
            const double a[8] = {A0.x, A0.y, A1.x, A1.y, A2.x, A2.y, A3.x, A3.y};
            const double b[8] = {B0.x, B0.y, B1.x, B1.y, B2.x, B2.y, B3.x, B3.y};
            #pragma unroll
            for (int i = 0; i < 8; ++i)
                #pragma unroll
                for (int j = 0; j < 8; ++j)
                    acc[i][j] = fma(a[i], b[j], acc[i][j]);
        }
        __syncthreads();
    }

    double bv[8];
    #pragma unroll
    for (int jb = 0; jb < 2; ++jb)
        #pragma unroll
        for (int j = 0; j < 4; ++j) {
            const int n = n0 + jb * 64 + tx * 4 + j;
            bv[jb * 4 + j] = (n < N) ? (double)bias[n] : 0.0;
        }

    #pragma unroll
    for (int ib = 0; ib < 2; ++ib)
        #pragma unroll
        for (int i = 0; i < 4; ++i) {
            const int m = m0 + ib * 64 + ty * 4 + i;
            #pragma unroll
            for (int jb = 0; jb < 2; ++jb) {
                const int n = n0 + jb * 64 + tx * 4;
                if (n < N) {
                    double v[4];
                    #pragma unroll
                    for (int j = 0; j < 4; ++j) {
                        double t = acc[ib * 4 + i][jb * 4 + j] + bv[jb * 4 + j];
                        if (ACT == 1) t = t > 0.0 ? t : 0.0;
                        v[j] = t;
                    }
                    if constexpr (std::is_same<TC, double>::value) {
                        double* cp = &C[(size_t)m * N + n];
                        *reinterpret_cast<double2*>(cp)     = make_double2(v[0], v[1]);
                        *reinterpret_cast<double2*>(cp + 2) = make_double2(v[2], v[3]);
                    } else {
                        float4 o, r;
                        float* oc = reinterpret_cast<float*>(&o);
                        float* rc = reinterpret_cast<float*>(&r);
                        #pragma unroll
                        for (int j = 0; j < 4; ++j) {
                            const float f = (float)v[j];
                            oc[j] = f;
                            rc[j] = (float)(v[j] - (double)f);
                        }
                        *reinterpret_cast<float4*>(&C[(size_t)m * N + n]) = o;
                        if (Res)
                            *reinterpret_cast<float4*>(&Res[(size_t)m * N + n]) = r;
                    }
                }
            }
        }
}

// ============================== VQ (f64 exact) ==============================
// z (per sample, per latent d) reconstructed as (double)z_e + (double)zres;
// d_n = ||W[:,n]||^2 - 2 z.W[:,n] in f64 -> argmin matches an exact (f64)
// reference. zres aliases the emb_o output section: read into LDS first,
// overwritten with z_q at the end of each sample's iteration.
__global__ __launch_bounds__(256) void vq_f64(
    const float* __restrict__ z_e, const float* __restrict__ zres,
    const float* __restrict__ Wemb, float* __restrict__ zq_out, int B)
{
    __shared__ float  Wsh[128 * 128];   // 64 KB, Wsh[k*128+n]
    __shared__ double zdsh[1024];       // 8 KB
    __shared__ int    idx_sh[8];

    const int tid = threadIdx.x;
    for (int i = tid; i < (128 * 128) / 4; i += 256)
        reinterpret_cast<float4*>(Wsh)[i] =
            reinterpret_cast<const float4*>(Wemb)[i];
    __syncthreads();

    const int wave = tid >> 6;
    const int lane = tid & 63;

    double wn0 = 0.0, wn1 = 0.0;
    for (int k = 0; k < 128; ++k) {
        const double w0 = (double)Wsh[k * 128 + lane];
        const double w1 = (double)Wsh[k * 128 + lane + 64];
        wn0 = fma(w0, w0, wn0);
        wn1 = fma(w1, w1, wn1);
    }

    for (int b = blockIdx.x; b < B; b += gridDim.x) {
        __syncthreads();   // previous iteration fully done with zdsh/idx_sh
        {
            const float4 z4 = reinterpret_cast<const float4*>(&z_e [(size_t)b * 1024])[tid];
            const float4 r4 = reinterpret_cast<const float4*>(&zres[(size_t)b * 1024])[tid];
            zdsh[tid * 4 + 0] = (double)z4.x + (double)r4.x;
            zdsh[tid * 4 + 1] = (double)z4.y + (double)r4.y;
            zdsh[tid * 4 + 2] = (double)z4.z + (double)r4.z;
            zdsh[tid * 4 + 3] = (double)z4.w + (double)r4.w;
        }
        __syncthreads();

        #pragma unroll
        for (int dd = 0; dd < 2; ++dd) {
            const int d = wave * 2 + dd;
            double s0 = 0.0, s1 = 0.0;
            for (int k = 0; k < 128; ++k) {
                const double z = zdsh[k * 8 + d];
                s0 = fma(z, (double)Wsh[k * 128 + lane], s0);
                s1 = fma(z, (double)Wsh[k * 128 + lane + 64], s1);
            }
            double v  = wn0 - 2.0 * s0;
            int   idx = lane;
            const double v1 = wn1 - 2.0 * s1;
            if (v1 < v) { v = v1; idx = lane + 64; }
            for (int off = 32; off > 0; off >>= 1) {
                const double ov = __shfl_down(v, off);
                const int    oi = __shfl_down(idx, off);
                if (ov < v || (ov == v && oi < idx)) { v = ov; idx = oi; }
            }
            if (lane == 0) idx_sh[d] = idx;
        }
        __syncthreads();

        float* outp = zq_out + (size_t)b * 1024;
        for (int i = tid; i < 1024; i += 256) {
            const int k = i >> 3;
            const int d = i & 7;
            outp[i] = Wsh[k * 128 + idx_sh[d]];
        }
    }
}

// ---------------------------------------------------------------------------
extern "C" void kernel_launch(void* const* d_in, const int* in_sizes, int n_in,
                              void* d_out, int out_size, void* d_ws, size_t ws_size,
                              hipStream_t stream)
{
    const float* x    = (const float*)d_in[0];
    const float* W1   = (const float*)d_in[1];
    const float* b1   = (const float*)d_in[2];
    const float* W2   = (const float*)d_in[3];
    const float* b2   = (const float*)d_in[4];
    const float* W3   = (const float*)d_in[5];
    const float* b3   = (const float*)d_in[6];
    const float* W4   = (const float*)d_in[7];
    const float* b4   = (const float*)d_in[8];
    const float* Wemb = (const float*)d_in[9];

    const int B = 16384;
    float* out   = (float*)d_out;
    float* recon = out;                                // B*3072
    float* z_e   = out + (size_t)B * 3072;             // B*1024
    float* emb_o = z_e + (size_t)B * 1024;             // B*1024: zres, then z_q

    const dim3 blk(256);
    const size_t h64_bytes = (size_t)B * 400 * sizeof(double);   // 52.4 MB

    if (ws_size >= h64_bytes) {
        double* h1d = (double*)d_ws;
        gemm_f64acc<1, float,  double><<<dim3(4, 128), blk, 0, stream>>>(
            x, W1, b1, h1d, nullptr, B, 400, 3072);
        gemm_f64acc<0, double, float ><<<dim3(8, 128), blk, 0, stream>>>(
            h1d, W2, b2, z_e, emb_o, B, 1024, 400);
    } else {
        float* h1 = (float*)d_ws;
        gemm_f64acc<1, float, float><<<dim3(4, 128), blk, 0, stream>>>(
            x, W1, b1, h1, nullptr, B, 400, 3072);
        gemm_f64acc<0, float, float><<<dim3(8, 128), blk, 0, stream>>>(
            h1, W2, b2, z_e, emb_o, B, 1024, 400);
    }

    // exact-argmin VQ; reads zres from emb_o section, overwrites it with z_q
    vq_f64<<<dim3(2048), blk, 0, stream>>>(z_e, emb_o, Wemb, emb_o, B);

    // decoder (fp32)
    float* h = (float*)d_ws;   // B*400 floats, fits in both ws cases
    gemm_f32<1><<<dim3(4, 128), blk, 0, stream>>>(emb_o, W3, b3, h, B, 400, 1024);
    gemm_f32<2><<<dim3(24, 128), blk, 0, stream>>>(h, W4, b4, recon, B, 3072, 400);
}

// Round 3
// 1686.168 us; speedup vs baseline: 1.3987x; 1.3987x over previous
//
#include <hip/hip_runtime.h>
#include <math.h>

// ---------------------------------------------------------------------------
// VQ-VAE forward on MI355X.
//   g1: h1  = relu(x @ W1^T + b1)      16384x400,  K=3072  [bf16x2-split MFMA]
//   g2: z_e = h1 @ W2^T + b2           16384x1024, K=400   [bf16x2-split MFMA]
//   vq: z_q = nearest(z_e, Wemb)       f64 distances from approx z_e,
//       top-2 gap < GAP_T -> flag sample for exact f64 recompute (fixup)
//   g3: h3  = relu(z_q @ W3^T + b3)    16384x400,  K=1024  [bf16 MFMA]
//   g4: recon = sigmoid(h3 @ W4^T+b4)  16384x3072, K=400   [bf16 MFMA]
// Outputs are bf16-compared with threshold 0.02: only argmin flips can fail;
// the gap-flag + exact fixup makes argmins exact regardless of GEMM noise.
// ---------------------------------------------------------------------------

typedef short bf16x8 __attribute__((ext_vector_type(8)));
typedef float f32x4  __attribute__((ext_vector_type(4)));

#define GAP_T 4e-3

__device__ __forceinline__ unsigned short f32_to_bf16_rn(float v) {
    union { float f; unsigned u; } c; c.f = v;
    unsigned r = c.u + 0x7FFFu + ((c.u >> 16) & 1u);
    return (unsigned short)(r >> 16);
}
__device__ __forceinline__ float bf16_bits_to_f32(unsigned short b) {
    union { unsigned u; float f; } c; c.u = ((unsigned)b) << 16;
    return c.f;
}

// ====================== split-bf16 MFMA GEMM (NT) ==========================
// C[M,N] = act(A[M,K] @ W[N,K]^T + bias).  NSPLIT=2: a=hi+lo, 3 products
// (hi*hi, hi*lo, lo*hi) -> ~2^-18 input capture. NSPLIT=1: plain bf16.
// Tile 128x128, BK=32, 256 thr = 4 waves (2x2), wave tile 64x64.
// LDS tiles [128 rows][32 bf16], 16B-slot XOR swizzle: slot' = slot ^ (row&3).
template<int NSPLIT, int ACT>
__global__ __launch_bounds__(256) void gemm_bf16s(
    const float* __restrict__ A, const float* __restrict__ W,
    const float* __restrict__ bias, float* __restrict__ C,
    int M, int N, int K)
{
    __shared__ short lds[NSPLIT * 2 * 128 * 32];   // A splits, then W splits

    const int tid  = threadIdx.x;
    const int lane = tid & 63;
    const int w_id = tid >> 6;
    const int wr   = (w_id >> 1) * 64;   // wave row offset in tile
    const int wc   = (w_id & 1)  * 64;   // wave col offset
    const int m0   = blockIdx.y * 128;
    const int n0   = blockIdx.x * 128;

    f32x4 acc[4][4];
    #pragma unroll
    for (int i = 0; i < 4; ++i)
        #pragma unroll
        for (int j = 0; j < 4; ++j) acc[i][j] = (f32x4){0.f, 0.f, 0.f, 0.f};

    for (int kt = 0; kt < K; kt += 32) {
        // ---------------- stage + split into LDS ----------------
        #pragma unroll
        for (int i = 0; i < 4; ++i) {
            const int f   = tid + i * 256;     // 0..1023
            const int row = f >> 3;            // 0..127
            const int c4  = (f & 7) << 2;      // 0,4,...,28
            const int kk  = kt + c4;

            float4 va = make_float4(0.f, 0.f, 0.f, 0.f);
            if (kk < K)
                va = *reinterpret_cast<const float4*>(&A[(size_t)(m0 + row) * K + kk]);
            float4 vw = make_float4(0.f, 0.f, 0.f, 0.f);
            if (kk < K && (n0 + row) < N)
                vw = *reinterpret_cast<const float4*>(&W[(size_t)(n0 + row) * K + kk]);

            // swizzled short index: row*32 + (slot ^ (row&3))*8 + (c4&4)
            const int bs = row * 32 + ((((c4 >> 3)) ^ (row & 3)) << 3) + (c4 & 4);

            float a[4] = {va.x, va.y, va.z, va.w};
            float w[4] = {vw.x, vw.y, vw.z, vw.w};
            #pragma unroll
            for (int s = 0; s < NSPLIT; ++s) {
                short4 pa, pw;
                short* pav = reinterpret_cast<short*>(&pa);
                short* pwv = reinterpret_cast<short*>(&pw);
                #pragma unroll
                for (int e = 0; e < 4; ++e) {
                    const unsigned short ha = f32_to_bf16_rn(a[e]);
                    const unsigned short hw = f32_to_bf16_rn(w[e]);
                    pav[e] = (short)ha;  pwv[e] = (short)hw;
                    if (NSPLIT > 1) {            // exact residual (Sterbenz)
                        a[e] -= bf16_bits_to_f32(ha);
                        w[e] -= bf16_bits_to_f32(hw);
                    }
                }
                *reinterpret_cast<short4*>(&lds[s * 4096 + bs]) = pa;
                *reinterpret_cast<short4*>(&lds[(NSPLIT + s) * 4096 + bs]) = pw;
            }
        }
        __syncthreads();

        // ---------------- fragments + MFMA ----------------
        bf16x8 bfr[4][NSPLIT];
        #pragma unroll
        for (int fc = 0; fc < 4; ++fc) {
            const int rn  = wc + fc * 16 + (lane & 15);
            const int idx = rn * 32 + (((lane >> 4) ^ (rn & 3)) << 3);
            #pragma unroll
            for (int s = 0; s < NSPLIT; ++s)
                bfr[fc][s] = *reinterpret_cast<const bf16x8*>(&lds[(NSPLIT + s) * 4096 + idx]);
        }
        #pragma unroll
        for (int fr = 0; fr < 4; ++fr) {
            const int rm  = wr + fr * 16 + (lane & 15);
            const int idx = rm * 32 + (((lane >> 4) ^ (rm & 3)) << 3);
            const bf16x8 a0 = *reinterpret_cast<const bf16x8*>(&lds[idx]);
            bf16x8 a1;
            if (NSPLIT > 1)
                a1 = *reinterpret_cast<const bf16x8*>(&lds[4096 + idx]);
            #pragma unroll
            for (int fc = 0; fc < 4; ++fc) {
                acc[fr][fc] = __builtin_amdgcn_mfma_f32_16x16x32_bf16(
                    a0, bfr[fc][0], acc[fr][fc], 0, 0, 0);
                if (NSPLIT > 1) {
                    acc[fr][fc] = __builtin_amdgcn_mfma_f32_16x16x32_bf16(
                        a0, bfr[fc][1], acc[fr][fc], 0, 0, 0);
                    acc[fr][fc] = __builtin_amdgcn_mfma_f32_16x16x32_bf16(
                        a1, bfr[fc][0], acc[fr][fc], 0, 0, 0);
                }
            }
        }
        __syncthreads();
    }

    // ---------------- epilogue ----------------
    float bv[4];
    #pragma unroll
    for (int fc = 0; fc < 4; ++fc) {
        const int col = n0 + wc + fc * 16 + (lane & 15);
        bv[fc] = (col < N) ? bias[col] : 0.f;
    }
    #pragma unroll
    for (int fr = 0; fr < 4; ++fr) {
        #pragma unroll
        for (int fc = 0; fc < 4; ++fc) {
            const int col = n0 + wc + fc * 16 + (lane & 15);
            if (col < N) {
                #pragma unroll
                for (int j = 0; j < 4; ++j) {
                    const int rowg = m0 + wr + fr * 16 + (lane >> 4) * 4 + j;
                    float v = acc[fr][fc][j] + bv[fc];
                    if (ACT == 1) v = fmaxf(v, 0.f);
                    else if (ACT == 2) v = 1.f / (1.f + expf(-v));
                    C[(size_t)rowg * N + col] = v;
                }
            }
        }
    }
}

// ============================ VQ with gap flagging ==========================
__global__ __launch_bounds__(256) void vq_flag(
    const float* __restrict__ z_e, const float* __restrict__ Wemb,
    float* __restrict__ zq_out, int* __restrict__ flag_cnt,
    int* __restrict__ flag_ids, int B)
{
    __shared__ float  Wsh[128 * 128];
    __shared__ double zdsh[1024];
    __shared__ int    idx_sh[8];
    __shared__ float  gap_sh[8];

    const int tid = threadIdx.x;
    for (int i = tid; i < (128 * 128) / 4; i += 256)
        reinterpret_cast<float4*>(Wsh)[i] =
            reinterpret_cast<const float4*>(Wemb)[i];
    __syncthreads();

    const int wave = tid >> 6;
    const int lane = tid & 63;

    double wn0 = 0.0, wn1 = 0.0;
    for (int k = 0; k < 128; ++k) {
        const double w0 = (double)Wsh[k * 128 + lane];
        const double w1 = (double)Wsh[k * 128 + lane + 64];
        wn0 = fma(w0, w0, wn0);
        wn1 = fma(w1, w1, wn1);
    }

    for (int b = blockIdx.x; b < B; b += gridDim.x) {
        __syncthreads();
        {
            const float4 z4 = reinterpret_cast<const float4*>(&z_e[(size_t)b * 1024])[tid];
            zdsh[tid * 4 + 0] = (double)z4.x;
            zdsh[tid * 4 + 1] = (double)z4.y;
            zdsh[tid * 4 + 2] = (double)z4.z;
            zdsh[tid * 4 + 3] = (double)z4.w;
        }
        __syncthreads();

        #pragma unroll
        for (int dd = 0; dd < 2; ++dd) {
            const int d = wave * 2 + dd;
            double s0 = 0.0, s1 = 0.0;
            for (int k = 0; k < 128; ++k) {
                const double z = zdsh[k * 8 + d];
                s0 = fma(z, (double)Wsh[k * 128 + lane], s0);
                s1 = fma(z, (double)Wsh[k * 128 + lane + 64], s1);
            }
            const double vA = wn0 - 2.0 * s0;
            const double vB = wn1 - 2.0 * s1;
            double v1, v2; int i1;
            if (vB < vA) { v1 = vB; i1 = lane + 64; v2 = vA; }
            else         { v1 = vA; i1 = lane;      v2 = vB; }
            // butterfly top-2 reduce (lowest index on v1 ties)
            #pragma unroll
            for (int off = 1; off < 64; off <<= 1) {
                const double ov1 = __shfl_xor(v1, off);
                const int    oi1 = __shfl_xor(i1, off);
                const double ov2 = __shfl_xor(v2, off);
                if (ov1 < v1 || (ov1 == v1 && oi1 < i1)) {
                    v2 = fmin(v1, ov2);
                    v1 = ov1; i1 = oi1;
                } else {
                    v2 = fmin(v2, ov1);
                }
            }
            if (lane == 0) { idx_sh[d] = i1; gap_sh[d] = (float)(v2 - v1); }
        }
        __syncthreads();

        if (tid == 0) {
            bool f = false;
            #pragma unroll
            for (int d = 0; d < 8; ++d) f |= (gap_sh[d] < (float)GAP_T);
            if (f) {
                const int p = atomicAdd(flag_cnt, 1);
                flag_ids[p] = b;
            }
        }

        float* outp = zq_out + (size_t)b * 1024;
        for (int i = tid; i < 1024; i += 256)
            outp[i] = Wsh[(i >> 3) * 128 + idx_sh[i & 7]];
    }
}

// ===================== exact f64 fixup for flagged samples ==================
__global__ __launch_bounds__(256) void vq_fixup(
    const float* __restrict__ x,  const float* __restrict__ W1,
    const float* __restrict__ b1, const float* __restrict__ W2,
    const float* __restrict__ b2, const float* __restrict__ Wemb,
    const int* __restrict__ flag_cnt, const int* __restrict__ flag_ids,
    float* __restrict__ zq_out)
{
    __shared__ float  xsh[3072];
    __shared__ double h1sh[400];
    __shared__ double zsh[1024];
    __shared__ double dist_sh[8 * 128];
    __shared__ int    idxf_sh[8];

    const int tid  = threadIdx.x;
    const int lane = tid & 63;
    const int wv   = tid >> 6;
    const int cnt  = *flag_cnt;

    for (int it = blockIdx.x; it < cnt; it += gridDim.x) {
        const int b = flag_ids[it];
        __syncthreads();
        for (int i = tid; i < 768; i += 256)
            reinterpret_cast<float4*>(xsh)[i] =
                reinterpret_cast<const float4*>(&x[(size_t)b * 3072])[i];
        __syncthreads();

        for (int j = tid; j < 400; j += 256) {
            double acc = (double)b1[j];
            const float4* wr = reinterpret_cast<const float4*>(&W1[(size_t)j * 3072]);
            for (int k4 = 0; k4 < 768; ++k4) {
                const float4 wv4 = wr[k4];
                const float4 xv  = *reinterpret_cast<const float4*>(&xsh[k4 * 4]);
                acc = fma((double)xv.x, (double)wv4.x, acc);
                acc = fma((double)xv.y, (double)wv4.y, acc);
                acc = fma((double)xv.z, (double)wv4.z, acc);
                acc = fma((double)xv.w, (double)wv4.w, acc);
            }
            h1sh[j] = acc > 0.0 ? acc : 0.0;
        }
        __syncthreads();

        for (int i = tid; i < 1024; i += 256) {
            double acc = (double)b2[i];
            const float4* wr = reinterpret_cast<const float4*>(&W2[(size_t)i * 400]);
            for (int j4 = 0; j4 < 100; ++j4) {
                const float4 wv4 = wr[j4];
                acc = fma(h1sh[j4 * 4 + 0], (double)wv4.x, acc);
                acc = fma(h1sh[j4 * 4 + 1], (double)wv4.y, acc);
                acc = fma(h1sh[j4 * 4 + 2], (double)wv4.z, acc);
                acc = fma(h1sh[j4 * 4 + 3], (double)wv4.w, acc);
            }
            zsh[i] = acc;
        }
        __syncthreads();

        for (int t = tid; t < 1024; t += 256) {
            const int d = t >> 7, n = t & 127;
            double s = 0.0;
            for (int k = 0; k < 128; ++k) {
                const double diff = zsh[k * 8 + d] - (double)Wemb[k * 128 + n];
                s = fma(diff, diff, s);
            }
            dist_sh[d * 128 + n] = s;
        }
        __syncthreads();

        for (int d = wv; d < 8; d += 4) {
            double v0 = dist_sh[d * 128 + lane], v1 = dist_sh[d * 128 + lane + 64];
            double v; int ix;
            if (v1 < v0) { v = v1; ix = lane + 64; }
            else         { v = v0; ix = lane; }
            for (int off = 32; off > 0; off >>= 1) {
                const double ov = __shfl_down(v, off);
                const int    oi = __shfl_down(ix, off);
                if (ov < v || (ov == v && oi < ix)) { v = ov; ix = oi; }
            }
            if (lane == 0) idxf_sh[d] = ix;
        }
        __syncthreads();

        for (int i = tid; i < 1024; i += 256)
            zq_out[(size_t)b * 1024 + i] = Wemb[(i >> 3) * 128 + idxf_sh[i & 7]];
    }
}

__global__ void zero_flags(int* flag_cnt) {
    if (threadIdx.x == 0 && blockIdx.x == 0) *flag_cnt = 0;
}

// ---------------------------------------------------------------------------
extern "C" void kernel_launch(void* const* d_in, const int* in_sizes, int n_in,
                              void* d_out, int out_size, void* d_ws, size_t ws_size,
                              hipStream_t stream)
{
    const float* x    = (const float*)d_in[0];
    const float* W1   = (const float*)d_in[1];
    const float* b1   = (const float*)d_in[2];
    const float* W2   = (const float*)d_in[3];
    const float* b2   = (const float*)d_in[4];
    const float* W3   = (const float*)d_in[5];
    const float* b3   = (const float*)d_in[6];
    const float* W4   = (const float*)d_in[7];
    const float* b4   = (const float*)d_in[8];
    const float* Wemb = (const float*)d_in[9];

    const int B = 16384;
    float* out   = (float*)d_out;
    float* recon = out;                                // B*3072
    float* z_e   = out + (size_t)B * 3072;             // B*1024
    float* emb_o = z_e + (size_t)B * 1024;             // B*1024 == z_q

    float* h        = (float*)d_ws;                            // B*400 (h1 then h3)
    int*   flag_cnt = (int*)((char*)d_ws + (32ull << 20));     // @32 MB
    int*   flag_ids = flag_cnt + 64;

    const dim3 blk(256);

    zero_flags<<<dim3(1), dim3(64), 0, stream>>>(flag_cnt);

    // encoder: bf16x2-split MFMA
    gemm_bf16s<2, 1><<<dim3(4, 128), blk, 0, stream>>>(x, W1, b1, h,   B, 400,  3072);
    gemm_bf16s<2, 0><<<dim3(8, 128), blk, 0, stream>>>(h, W2, b2, z_e, B, 1024, 400);

    // VQ (f64 distances, top-2 gap flagging) + exact fixup
    vq_flag<<<dim3(2048), blk, 0, stream>>>(z_e, Wemb, emb_o, flag_cnt, flag_ids, B);
    vq_fixup<<<dim3(256), blk, 0, stream>>>(x, W1, b1, W2, b2, Wemb,
                                            flag_cnt, flag_ids, emb_o);

    // decoder: plain bf16 MFMA
    gemm_bf16s<1, 1><<<dim3(4, 128),  blk, 0, stream>>>(emb_o, W3, b3, h,     B, 400,  1024);
    gemm_bf16s<1, 2><<<dim3(24, 128), blk, 0, stream>>>(h,     W4, b4, recon, B, 3072, 400);
}

// Round 4
// 1322.191 us; speedup vs baseline: 1.7838x; 1.2753x over previous
//
#include <hip/hip_runtime.h>
#include <math.h>

// ---------------------------------------------------------------------------
// VQ-VAE forward on MI355X.
//   g1: h1  = relu(x @ W1^T + b1)      16384x400,  K=3072  [bf16x2-split MFMA]
//   g2: z_e = h1 @ W2^T + b2           16384x1024, K=400   [bf16x2-split MFMA]
//   vq: z_q = nearest(z_e, Wemb)       f32 dots + f64 compare; top-2 gap
//       < GAP_T (=2e-4, ~14 sigma of our distance error) -> exact f64 fixup
//   g3: h3  = relu(z_q @ W3^T + b3)    16384x400,  K=1024  [bf16 MFMA]
//   g4: recon = sigmoid(h3 @ W4^T+b4)  16384x3072, K=400   [bf16 MFMA]
// Outputs are bf16-compared (thr 0.02): only argmin flips can fail; the
// gap-flag + exact fixup makes argmins exact regardless of GEMM noise.
// Round-4 change: GAP_T 4e-3 -> 2e-4 (flag rate ~20x down), batched fixup
// (4 samples/block, 512 thr), vq_flag inner loop f32 with transposed LDS.
// ---------------------------------------------------------------------------

typedef short bf16x8 __attribute__((ext_vector_type(8)));
typedef float f32x4  __attribute__((ext_vector_type(4)));

#define GAP_T 2e-4

__device__ __forceinline__ unsigned short f32_to_bf16_rn(float v) {
    union { float f; unsigned u; } c; c.f = v;
    unsigned r = c.u + 0x7FFFu + ((c.u >> 16) & 1u);
    return (unsigned short)(r >> 16);
}
__device__ __forceinline__ float bf16_bits_to_f32(unsigned short b) {
    union { unsigned u; float f; } c; c.u = ((unsigned)b) << 16;
    return c.f;
}

// ====================== split-bf16 MFMA GEMM (NT) ==========================
// C[M,N] = act(A[M,K] @ W[N,K]^T + bias).  NSPLIT=2: a=hi+lo, 3 products
// (hi*hi, hi*lo, lo*hi) -> ~2^-18 input capture. NSPLIT=1: plain bf16.
// Tile 128x128, BK=32, 256 thr = 4 waves (2x2), wave tile 64x64.
template<int NSPLIT, int ACT>
__global__ __launch_bounds__(256) void gemm_bf16s(
    const float* __restrict__ A, const float* __restrict__ W,
    const float* __restrict__ bias, float* __restrict__ C,
    int M, int N, int K)
{
    __shared__ short lds[NSPLIT * 2 * 128 * 32];   // A splits, then W splits

    const int tid  = threadIdx.x;
    const int lane = tid & 63;
    const int w_id = tid >> 6;
    const int wr   = (w_id >> 1) * 64;
    const int wc   = (w_id & 1)  * 64;
    const int m0   = blockIdx.y * 128;
    const int n0   = blockIdx.x * 128;

    f32x4 acc[4][4];
    #pragma unroll
    for (int i = 0; i < 4; ++i)
        #pragma unroll
        for (int j = 0; j < 4; ++j) acc[i][j] = (f32x4){0.f, 0.f, 0.f, 0.f};

    for (int kt = 0; kt < K; kt += 32) {
        #pragma unroll
        for (int i = 0; i < 4; ++i) {
            const int f   = tid + i * 256;
            const int row = f >> 3;
            const int c4  = (f & 7) << 2;
            const int kk  = kt + c4;

            float4 va = make_float4(0.f, 0.f, 0.f, 0.f);
            if (kk < K)
                va = *reinterpret_cast<const float4*>(&A[(size_t)(m0 + row) * K + kk]);
            float4 vw = make_float4(0.f, 0.f, 0.f, 0.f);
            if (kk < K && (n0 + row) < N)
                vw = *reinterpret_cast<const float4*>(&W[(size_t)(n0 + row) * K + kk]);

            const int bs = row * 32 + ((((c4 >> 3)) ^ (row & 3)) << 3) + (c4 & 4);

            float a[4] = {va.x, va.y, va.z, va.w};
            float w[4] = {vw.x, vw.y, vw.z, vw.w};
            #pragma unroll
            for (int s = 0; s < NSPLIT; ++s) {
                short4 pa, pw;
                short* pav = reinterpret_cast<short*>(&pa);
                short* pwv = reinterpret_cast<short*>(&pw);
                #pragma unroll
                for (int e = 0; e < 4; ++e) {
                    const unsigned short ha = f32_to_bf16_rn(a[e]);
                    const unsigned short hw = f32_to_bf16_rn(w[e]);
                    pav[e] = (short)ha;  pwv[e] = (short)hw;
                    if (NSPLIT > 1) {
                        a[e] -= bf16_bits_to_f32(ha);
                        w[e] -= bf16_bits_to_f32(hw);
                    }
                }
                *reinterpret_cast<short4*>(&lds[s * 4096 + bs]) = pa;
                *reinterpret_cast<short4*>(&lds[(NSPLIT + s) * 4096 + bs]) = pw;
            }
        }
        __syncthreads();

        bf16x8 bfr[4][NSPLIT];
        #pragma unroll
        for (int fc = 0; fc < 4; ++fc) {
            const int rn  = wc + fc * 16 + (lane & 15);
            const int idx = rn * 32 + (((lane >> 4) ^ (rn & 3)) << 3);
            #pragma unroll
            for (int s = 0; s < NSPLIT; ++s)
                bfr[fc][s] = *reinterpret_cast<const bf16x8*>(&lds[(NSPLIT + s) * 4096 + idx]);
        }
        #pragma unroll
        for (int fr = 0; fr < 4; ++fr) {
            const int rm  = wr + fr * 16 + (lane & 15);
            const int idx = rm * 32 + (((lane >> 4) ^ (rm & 3)) << 3);
            const bf16x8 a0 = *reinterpret_cast<const bf16x8*>(&lds[idx]);
            bf16x8 a1;
            if (NSPLIT > 1)
                a1 = *reinterpret_cast<const bf16x8*>(&lds[4096 + idx]);
            #pragma unroll
            for (int fc = 0; fc < 4; ++fc) {
                acc[fr][fc] = __builtin_amdgcn_mfma_f32_16x16x32_bf16(
                    a0, bfr[fc][0], acc[fr][fc], 0, 0, 0);
                if (NSPLIT > 1) {
                    acc[fr][fc] = __builtin_amdgcn_mfma_f32_16x16x32_bf16(
                        a0, bfr[fc][1], acc[fr][fc], 0, 0, 0);
                    acc[fr][fc] = __builtin_amdgcn_mfma_f32_16x16x32_bf16(
                        a1, bfr[fc][0], acc[fr][fc], 0, 0, 0);
                }
            }
        }
        __syncthreads();
    }

    float bv[4];
    #pragma unroll
    for (int fc = 0; fc < 4; ++fc) {
        const int col = n0 + wc + fc * 16 + (lane & 15);
        bv[fc] = (col < N) ? bias[col] : 0.f;
    }
    #pragma unroll
    for (int fr = 0; fr < 4; ++fr) {
        #pragma unroll
        for (int fc = 0; fc < 4; ++fc) {
            const int col = n0 + wc + fc * 16 + (lane & 15);
            if (col < N) {
                #pragma unroll
                for (int j = 0; j < 4; ++j) {
                    const int rowg = m0 + wr + fr * 16 + (lane >> 4) * 4 + j;
                    float v = acc[fr][fc][j] + bv[fc];
                    if (ACT == 1) v = fmaxf(v, 0.f);
                    else if (ACT == 2) v = 1.f / (1.f + expf(-v));
                    C[(size_t)rowg * N + col] = v;
                }
            }
        }
    }
}

// ============================ VQ with gap flagging ==========================
// Transposed codebook Wt[n][k] (pitch 132 -> 16B-aligned rows, bank-balanced
// b128 reads). Dots in f32 (error ~2e-8 << GAP_T); norms/compare in f64.
__global__ __launch_bounds__(256) void vq_flag(
    const float* __restrict__ z_e, const float* __restrict__ Wemb,
    float* __restrict__ zq_out, int* __restrict__ flag_cnt,
    int* __restrict__ flag_ids, int B)
{
    __shared__ float Wt[128 * 132];   // Wt[n*132+k] = Wemb[k*128+n], 67.6 KB
    __shared__ float zt[8 * 132];     // zt[d*132+k] = z[k*8+d]
    __shared__ int   idx_sh[8];
    __shared__ float gap_sh[8];

    const int tid = threadIdx.x;
    for (int i = tid; i < 4096; i += 256) {
        const int k  = i >> 5;
        const int n4 = (i & 31) << 2;
        const float4 w = *reinterpret_cast<const float4*>(&Wemb[k * 128 + n4]);
        Wt[(n4 + 0) * 132 + k] = w.x;
        Wt[(n4 + 1) * 132 + k] = w.y;
        Wt[(n4 + 2) * 132 + k] = w.z;
        Wt[(n4 + 3) * 132 + k] = w.w;
    }
    __syncthreads();

    const int wave = tid >> 6;
    const int lane = tid & 63;

    // f64 column norms for columns lane, lane+64
    double wn0 = 0.0, wn1 = 0.0;
    for (int k4 = 0; k4 < 32; ++k4) {
        const float4 a = *reinterpret_cast<const float4*>(&Wt[lane * 132 + 4 * k4]);
        const float4 c = *reinterpret_cast<const float4*>(&Wt[(lane + 64) * 132 + 4 * k4]);
        wn0 += (double)a.x * a.x + (double)a.y * a.y + (double)a.z * a.z + (double)a.w * a.w;
        wn1 += (double)c.x * c.x + (double)c.y * c.y + (double)c.z * c.z + (double)c.w * c.w;
    }

    for (int b = blockIdx.x; b < B; b += gridDim.x) {
        __syncthreads();
        {   // stage z transposed: element i -> (k=i>>3, d=i&7)
            const float4 z4 = reinterpret_cast<const float4*>(&z_e[(size_t)b * 1024])[tid];
            const int k  = tid >> 1;
            const int d0 = (tid & 1) * 4;
            zt[(d0 + 0) * 132 + k] = z4.x;
            zt[(d0 + 1) * 132 + k] = z4.y;
            zt[(d0 + 2) * 132 + k] = z4.z;
            zt[(d0 + 3) * 132 + k] = z4.w;
        }
        __syncthreads();

        float s[2][2] = {{0.f, 0.f}, {0.f, 0.f}};
        for (int k4 = 0; k4 < 32; ++k4) {
            const float4 a = *reinterpret_cast<const float4*>(&Wt[lane * 132 + 4 * k4]);
            const float4 c = *reinterpret_cast<const float4*>(&Wt[(lane + 64) * 132 + 4 * k4]);
            #pragma unroll
            for (int dd = 0; dd < 2; ++dd) {
                const float4 zv = *reinterpret_cast<const float4*>(
                    &zt[(wave * 2 + dd) * 132 + 4 * k4]);
                s[dd][0] = fmaf(zv.x, a.x, s[dd][0]);
                s[dd][0] = fmaf(zv.y, a.y, s[dd][0]);
                s[dd][0] = fmaf(zv.z, a.z, s[dd][0]);
                s[dd][0] = fmaf(zv.w, a.w, s[dd][0]);
                s[dd][1] = fmaf(zv.x, c.x, s[dd][1]);
                s[dd][1] = fmaf(zv.y, c.y, s[dd][1]);
                s[dd][1] = fmaf(zv.z, c.z, s[dd][1]);
                s[dd][1] = fmaf(zv.w, c.w, s[dd][1]);
            }
        }

        #pragma unroll
        for (int dd = 0; dd < 2; ++dd) {
            const int d = wave * 2 + dd;
            const double vA = wn0 - 2.0 * (double)s[dd][0];
            const double vB = wn1 - 2.0 * (double)s[dd][1];
            double v1, v2; int i1;
            if (vB < vA) { v1 = vB; i1 = lane + 64; v2 = vA; }
            else         { v1 = vA; i1 = lane;      v2 = vB; }
            #pragma unroll
            for (int off = 1; off < 64; off <<= 1) {
                const double ov1 = __shfl_xor(v1, off);
                const int    oi1 = __shfl_xor(i1, off);
                const double ov2 = __shfl_xor(v2, off);
                if (ov1 < v1 || (ov1 == v1 && oi1 < i1)) {
                    v2 = fmin(v1, ov2);
                    v1 = ov1; i1 = oi1;
                } else {
                    v2 = fmin(v2, ov1);
                }
            }
            if (lane == 0) { idx_sh[d] = i1; gap_sh[d] = (float)(v2 - v1); }
        }
        __syncthreads();

        if (tid == 0) {
            bool f = false;
            #pragma unroll
            for (int d = 0; d < 8; ++d) f |= (gap_sh[d] < (float)GAP_T);
            if (f) {
                const int p = atomicAdd(flag_cnt, 1);
                flag_ids[p] = b;
            }
        }
        float* outp = zq_out + (size_t)b * 1024;
        for (int i = tid; i < 1024; i += 256)
            outp[i] = Wt[idx_sh[i & 7] * 132 + (i >> 3)];
    }
}

// ===================== exact f64 fixup (batched, 4 samples/block) ===========
__global__ __launch_bounds__(512) void vq_fixup(
    const float* __restrict__ x,  const float* __restrict__ W1,
    const float* __restrict__ b1, const float* __restrict__ W2,
    const float* __restrict__ b2, const float* __restrict__ Wemb,
    const int* __restrict__ flag_cnt, const int* __restrict__ flag_ids,
    float* __restrict__ zq_out)
{
    // manually-aliased smem: [0,48K) x4 f32 -> later zsh[4][1024] f64 @ [0,32K)
    // [48K,60.95K) h1sh[4][400] f64; dist[4][8][128] f64 @ [32K,64K)
    __shared__ char smem[65536];
    float*  xsh  = reinterpret_cast<float*>(smem);
    double* h1sh = reinterpret_cast<double*>(smem + 49152);
    double* zsh  = reinterpret_cast<double*>(smem);
    double* dist = reinterpret_cast<double*>(smem + 32768);
    __shared__ int idxf[4][8];

    const int tid  = threadIdx.x;
    const int lane = tid & 63;
    const int wv   = tid >> 6;
    const int cnt  = *flag_cnt;

    for (int base = blockIdx.x * 4; base < cnt; base += gridDim.x * 4) {
        const int ns = min(4, cnt - base);
        __syncthreads();
        // ---- stage x ----
        for (int i = tid; i < ns * 768; i += 512) {
            const int s = i / 768, k4 = i - s * 768;
            reinterpret_cast<float4*>(xsh)[s * 768 + k4] =
                reinterpret_cast<const float4*>(
                    &x[(size_t)flag_ids[base + s] * 3072])[k4];
        }
        __syncthreads();
        // ---- exact h1 (f64), 4 samples per W1-row pass ----
        for (int j = tid; j < 400; j += 512) {
            double acc[4];
            #pragma unroll
            for (int s = 0; s < 4; ++s) acc[s] = (double)b1[j];
            const float4* wr = reinterpret_cast<const float4*>(&W1[(size_t)j * 3072]);
            for (int k4 = 0; k4 < 768; ++k4) {
                const float4 w = wr[k4];
                #pragma unroll
                for (int s = 0; s < 4; ++s) {
                    const float4 xv = reinterpret_cast<const float4*>(xsh)[s * 768 + k4];
                    acc[s] = fma((double)xv.x, (double)w.x, acc[s]);
                    acc[s] = fma((double)xv.y, (double)w.y, acc[s]);
                    acc[s] = fma((double)xv.z, (double)w.z, acc[s]);
                    acc[s] = fma((double)xv.w, (double)w.w, acc[s]);
                }
            }
            #pragma unroll
            for (int s = 0; s < 4; ++s)
                if (s < ns) h1sh[s * 400 + j] = acc[s] > 0.0 ? acc[s] : 0.0;
        }
        __syncthreads();
        // ---- exact z (f64), W2 row shared across samples ----
        for (int zi = tid; zi < 1024; zi += 512) {
            double acc[4];
            #pragma unroll
            for (int s = 0; s < 4; ++s) acc[s] = (double)b2[zi];
            const float4* wr = reinterpret_cast<const float4*>(&W2[(size_t)zi * 400]);
            for (int j4 = 0; j4 < 100; ++j4) {
                const float4 w = wr[j4];
                #pragma unroll
                for (int s = 0; s < 4; ++s) {
                    const double* hp = &h1sh[s * 400 + j4 * 4];
                    acc[s] = fma(hp[0], (double)w.x, acc[s]);
                    acc[s] = fma(hp[1], (double)w.y, acc[s]);
                    acc[s] = fma(hp[2], (double)w.z, acc[s]);
                    acc[s] = fma(hp[3], (double)w.w, acc[s]);
                }
            }
            // xsh region is dead; zsh aliases it
            #pragma unroll
            for (int s = 0; s < 4; ++s)
                if (s < ns) zsh[s * 1024 + zi] = acc[s];
        }
        __syncthreads();
        // ---- exact distances ----
        for (int t = tid; t < ns * 1024; t += 512) {
            const int n = t & 127, d = (t >> 7) & 7, s = t >> 10;
            double acc = 0.0;
            for (int k = 0; k < 128; ++k) {
                const double diff = zsh[s * 1024 + k * 8 + d] - (double)Wemb[k * 128 + n];
                acc = fma(diff, diff, acc);
            }
            dist[(s * 8 + d) * 128 + n] = acc;
        }
        __syncthreads();
        // ---- argmin per (sample, latent) ----
        for (int p = wv; p < ns * 8; p += 8) {
            const double* dp = &dist[p * 128];
            double v0 = dp[lane], vx = dp[lane + 64];
            double v; int ix;
            if (vx < v0) { v = vx; ix = lane + 64; }
            else         { v = v0; ix = lane; }
            for (int off = 32; off > 0; off >>= 1) {
                const double ov = __shfl_down(v, off);
                const int    oi = __shfl_down(ix, off);
                if (ov < v || (ov == v && oi < ix)) { v = ov; ix = oi; }
            }
            if (lane == 0) idxf[p >> 3][p & 7] = ix;
        }
        __syncthreads();
        // ---- rewrite z_q for flagged samples ----
        for (int i = tid; i < ns * 1024; i += 512) {
            const int s = i >> 10, zi = i & 1023;
            zq_out[(size_t)flag_ids[base + s] * 1024 + zi] =
                Wemb[(zi >> 3) * 128 + idxf[s][zi & 7]];
        }
    }
}

__global__ void zero_flags(int* flag_cnt) {
    if (threadIdx.x == 0 && blockIdx.x == 0) *flag_cnt = 0;
}

// ---------------------------------------------------------------------------
extern "C" void kernel_launch(void* const* d_in, const int* in_sizes, int n_in,
                              void* d_out, int out_size, void* d_ws, size_t ws_size,
                              hipStream_t stream)
{
    const float* x    = (const float*)d_in[0];
    const float* W1   = (const float*)d_in[1];
    const float* b1   = (const float*)d_in[2];
    const float* W2   = (const float*)d_in[3];
    const float* b2   = (const float*)d_in[4];
    const float* W3   = (const float*)d_in[5];
    const float* b3   = (const float*)d_in[6];
    const float* W4   = (const float*)d_in[7];
    const float* b4   = (const float*)d_in[8];
    const float* Wemb = (const float*)d_in[9];

    const int B = 16384;
    float* out   = (float*)d_out;
    float* recon = out;                                // B*3072
    float* z_e   = out + (size_t)B * 3072;             // B*1024
    float* emb_o = z_e + (size_t)B * 1024;             // B*1024 == z_q

    float* h        = (float*)d_ws;                            // B*400 (h1 then h3)
    int*   flag_cnt = (int*)((char*)d_ws + (32ull << 20));     // @32 MB
    int*   flag_ids = flag_cnt + 64;

    const dim3 blk(256);

    zero_flags<<<dim3(1), dim3(64), 0, stream>>>(flag_cnt);

    // encoder: bf16x2-split MFMA
    gemm_bf16s<2, 1><<<dim3(4, 128), blk, 0, stream>>>(x, W1, b1, h,   B, 400,  3072);
    gemm_bf16s<2, 0><<<dim3(8, 128), blk, 0, stream>>>(h, W2, b2, z_e, B, 1024, 400);

    // VQ (f32 dots, f64 compare, top-2 gap flagging) + exact batched fixup
    vq_flag<<<dim3(2048), blk, 0, stream>>>(z_e, Wemb, emb_o, flag_cnt, flag_ids, B);
    vq_fixup<<<dim3(512), dim3(512), 0, stream>>>(x, W1, b1, W2, b2, Wemb,
                                                  flag_cnt, flag_ids, emb_o);

    // decoder: plain bf16 MFMA
    gemm_bf16s<1, 1><<<dim3(4, 128),  blk, 0, stream>>>(emb_o, W3, b3, h,     B, 400,  1024);
    gemm_bf16s<1, 2><<<dim3(24, 128), blk, 0, stream>>>(h,     W4, b4, recon, B, 3072, 400);
}

// Round 5
// 1059.299 us; speedup vs baseline: 2.2264x; 1.2482x over previous
//
#include <hip/hip_runtime.h>
#include <math.h>

// ---------------------------------------------------------------------------
// VQ-VAE forward on MI355X.
//   g1: h1  = relu(x @ W1^T + b1)      16384x400,  K=3072  [bf16x2-split MFMA]
//   g2: z_e = h1 @ W2^T + b2           16384x1024, K=400   [bf16x2-split MFMA]
//   vq: S = Z' @ Wemb as bf16x2 MFMA GEMM (131072x128x128), fused f64
//       epilogue v = ||W_n||^2 - 2S, top-2 argmin; gap < GAP_T -> exact fixup
//   g3: h3  = relu(z_q @ W3^T + b3)    16384x400,  K=1024  [bf16 MFMA]
//   g4: recon = sigmoid(h3 @ W4^T+b4)  16384x3072, K=400   [bf16 MFMA]
// Round-5 change: vq_flag (390us, LDS-traffic/latency-bound: per-sample
// codebook re-reads) -> vq_mfma (codebook staged once per 16-sample block,
// swizzled-source z transpose, MFMA dots, fused top-2 argmin epilogue).
// ---------------------------------------------------------------------------

typedef short bf16x8 __attribute__((ext_vector_type(8)));
typedef float f32x4  __attribute__((ext_vector_type(4)));

#define GAP_T 2e-4

__device__ __forceinline__ unsigned short f32_to_bf16_rn(float v) {
    union { float f; unsigned u; } c; c.f = v;
    unsigned r = c.u + 0x7FFFu + ((c.u >> 16) & 1u);
    return (unsigned short)(r >> 16);
}
__device__ __forceinline__ float bf16_bits_to_f32(unsigned short b) {
    union { unsigned u; float f; } c; c.u = ((unsigned)b) << 16;
    return c.f;
}

// ====================== split-bf16 MFMA GEMM (NT) ==========================
// (unchanged from round 4 — known good)
template<int NSPLIT, int ACT>
__global__ __launch_bounds__(256) void gemm_bf16s(
    const float* __restrict__ A, const float* __restrict__ W,
    const float* __restrict__ bias, float* __restrict__ C,
    int M, int N, int K)
{
    __shared__ short lds[NSPLIT * 2 * 128 * 32];

    const int tid  = threadIdx.x;
    const int lane = tid & 63;
    const int w_id = tid >> 6;
    const int wr   = (w_id >> 1) * 64;
    const int wc   = (w_id & 1)  * 64;
    const int m0   = blockIdx.y * 128;
    const int n0   = blockIdx.x * 128;

    f32x4 acc[4][4];
    #pragma unroll
    for (int i = 0; i < 4; ++i)
        #pragma unroll
        for (int j = 0; j < 4; ++j) acc[i][j] = (f32x4){0.f, 0.f, 0.f, 0.f};

    for (int kt = 0; kt < K; kt += 32) {
        #pragma unroll
        for (int i = 0; i < 4; ++i) {
            const int f   = tid + i * 256;
            const int row = f >> 3;
            const int c4  = (f & 7) << 2;
            const int kk  = kt + c4;

            float4 va = make_float4(0.f, 0.f, 0.f, 0.f);
            if (kk < K)
                va = *reinterpret_cast<const float4*>(&A[(size_t)(m0 + row) * K + kk]);
            float4 vw = make_float4(0.f, 0.f, 0.f, 0.f);
            if (kk < K && (n0 + row) < N)
                vw = *reinterpret_cast<const float4*>(&W[(size_t)(n0 + row) * K + kk]);

            const int bs = row * 32 + ((((c4 >> 3)) ^ (row & 3)) << 3) + (c4 & 4);

            float a[4] = {va.x, va.y, va.z, va.w};
            float w[4] = {vw.x, vw.y, vw.z, vw.w};
            #pragma unroll
            for (int s = 0; s < NSPLIT; ++s) {
                short4 pa, pw;
                short* pav = reinterpret_cast<short*>(&pa);
                short* pwv = reinterpret_cast<short*>(&pw);
                #pragma unroll
                for (int e = 0; e < 4; ++e) {
                    const unsigned short ha = f32_to_bf16_rn(a[e]);
                    const unsigned short hw = f32_to_bf16_rn(w[e]);
                    pav[e] = (short)ha;  pwv[e] = (short)hw;
                    if (NSPLIT > 1) {
                        a[e] -= bf16_bits_to_f32(ha);
                        w[e] -= bf16_bits_to_f32(hw);
                    }
                }
                *reinterpret_cast<short4*>(&lds[s * 4096 + bs]) = pa;
                *reinterpret_cast<short4*>(&lds[(NSPLIT + s) * 4096 + bs]) = pw;
            }
        }
        __syncthreads();

        bf16x8 bfr[4][NSPLIT];
        #pragma unroll
        for (int fc = 0; fc < 4; ++fc) {
            const int rn  = wc + fc * 16 + (lane & 15);
            const int idx = rn * 32 + (((lane >> 4) ^ (rn & 3)) << 3);
            #pragma unroll
            for (int s = 0; s < NSPLIT; ++s)
                bfr[fc][s] = *reinterpret_cast<const bf16x8*>(&lds[(NSPLIT + s) * 4096 + idx]);
        }
        #pragma unroll
        for (int fr = 0; fr < 4; ++fr) {
            const int rm  = wr + fr * 16 + (lane & 15);
            const int idx = rm * 32 + (((lane >> 4) ^ (rm & 3)) << 3);
            const bf16x8 a0 = *reinterpret_cast<const bf16x8*>(&lds[idx]);
            bf16x8 a1;
            if (NSPLIT > 1)
                a1 = *reinterpret_cast<const bf16x8*>(&lds[4096 + idx]);
            #pragma unroll
            for (int fc = 0; fc < 4; ++fc) {
                acc[fr][fc] = __builtin_amdgcn_mfma_f32_16x16x32_bf16(
                    a0, bfr[fc][0], acc[fr][fc], 0, 0, 0);
                if (NSPLIT > 1) {
                    acc[fr][fc] = __builtin_amdgcn_mfma_f32_16x16x32_bf16(
                        a0, bfr[fc][1], acc[fr][fc], 0, 0, 0);
                    acc[fr][fc] = __builtin_amdgcn_mfma_f32_16x16x32_bf16(
                        a1, bfr[fc][0], acc[fr][fc], 0, 0, 0);
                }
            }
        }
        __syncthreads();
    }

    float bv[4];
    #pragma unroll
    for (int fc = 0; fc < 4; ++fc) {
        const int col = n0 + wc + fc * 16 + (lane & 15);
        bv[fc] = (col < N) ? bias[col] : 0.f;
    }
    #pragma unroll
    for (int fr = 0; fr < 4; ++fr) {
        #pragma unroll
        for (int fc = 0; fc < 4; ++fc) {
            const int col = n0 + wc + fc * 16 + (lane & 15);
            if (col < N) {
                #pragma unroll
                for (int j = 0; j < 4; ++j) {
                    const int rowg = m0 + wr + fr * 16 + (lane >> 4) * 4 + j;
                    float v = acc[fr][fc][j] + bv[fc];
                    if (ACT == 1) v = fmaxf(v, 0.f);
                    else if (ACT == 2) v = 1.f / (1.f + expf(-v));
                    C[(size_t)rowg * N + col] = v;
                }
            }
        }
    }
}

// ============================ VQ prep (one block) ===========================
// Builds: (a) Wemb split planes in B-tile layout [n][k] bf16, pre-swizzled
// (slot' = slot ^ (n&7), slot = 16B unit of 8 bf16) so vq_mfma stages them
// with a plain linear 64KB copy; (b) f64 column norms; (c) flag_cnt = 0.
__global__ void vq_prep(const float* __restrict__ Wemb, short* __restrict__ planes,
                        double* __restrict__ wn, int* __restrict__ flag_cnt)
{
    const int tid = threadIdx.x;   // 256 threads, 1 block
    if (tid == 0) *flag_cnt = 0;
    if (tid < 128) {
        double s = 0.0;
        for (int k = 0; k < 128; ++k) {
            const double w = (double)Wemb[k * 128 + tid];
            s = fma(w, w, s);
        }
        wn[tid] = s;
    }
    for (int t = tid; t < 16384; t += 256) {
        const int k = t >> 7, n = t & 127;
        const float w = Wemb[t];
        const unsigned short hi = f32_to_bf16_rn(w);
        const unsigned short lo = f32_to_bf16_rn(w - bf16_bits_to_f32(hi));
        const int off = n * 128 + (((k >> 3) ^ (n & 7)) << 3) + (k & 7);
        planes[off]         = (short)hi;
        planes[16384 + off] = (short)lo;
    }
}

// ============================ VQ MFMA + argmin ==============================
// Block: 512 thr (8 waves, 4 row-groups x 2 col-halves), 16 samples.
// A = Z'[(b,d),k] transposed-read from swizzled-staged z rows; B = Wemb
// splits from prep planes. S via 3-product bf16x2 MFMA (err ~4e-6).
// Epilogue: v_n = wn[n] - 2 S (f64), fused top-2 argmin, gap flagging,
// z_q gather-write (exact f32 = hi+lo reconstruction).
__global__ __launch_bounds__(512) void vq_mfma(
    const float* __restrict__ z_e, const short* __restrict__ planes,
    const double* __restrict__ wn_g, float* __restrict__ zq,
    int* __restrict__ flag_cnt, int* __restrict__ flag_ids)
{
    __shared__ short  Wsh[32768];        // hi [0,16384), lo [16384,32768)  64KB
    __shared__ float  zsh[16 * 1024];    // swizzled z rows                 64KB
    __shared__ double wn_sh[128];
    __shared__ double cmb_v1[128][2];
    __shared__ double cmb_v2[128][2];
    __shared__ int    cmb_i[128][2];
    __shared__ int    idx_sh[128];
    __shared__ int    sflag[16];

    const int tid = threadIdx.x;
    const int b0  = blockIdx.x * 16;

    // ---- stage W planes: linear 64KB copy (prep pre-swizzled them) ----
    for (int c = tid; c < 4096; c += 512)
        *reinterpret_cast<int4*>(&Wsh[c * 8]) =
            *reinterpret_cast<const int4*>(&planes[c * 8]);
    for (int c = tid; c < 128; c += 512) wn_sh[c] = wn_g[c];
    // ---- stage z: linear LDS dest, XOR-swizzled global source ----
    // LDS byte L = 4i ^ (((i>>6)&3)<<5) holds element i=k*8+d of its sample
    // (involution on bits 5-6 keyed by bits 8-9) -> stride-32 transpose reads
    // are bank-conflict-free.
    for (int c = tid; c < 4096; c += 512) {
        const int D    = c * 16;
        const int s    = D >> 12;
        const int dr   = D & 4095;
        const int srcb = dr ^ (((dr >> 8) & 3) << 5);
        *reinterpret_cast<int4*>(reinterpret_cast<char*>(zsh) + D) =
            *reinterpret_cast<const int4*>(
                reinterpret_cast<const char*>(z_e) + (size_t)(b0 + s) * 4096 + srcb);
    }
    if (tid < 16) sflag[tid] = 0;
    __syncthreads();

    const int lane = tid & 63;
    const int w_id = tid >> 6;          // 0..7
    const int wr   = (w_id >> 1) * 32;  // wave rows: 32
    const int wc   = (w_id & 1) * 64;   // wave cols: 64
    const int l15  = lane & 15;
    const int lg   = lane >> 4;         // 0..3

    f32x4 acc[2][4];
    #pragma unroll
    for (int i = 0; i < 2; ++i)
        #pragma unroll
        for (int j = 0; j < 4; ++j) acc[i][j] = (f32x4){0.f, 0.f, 0.f, 0.f};

    #pragma unroll
    for (int ks = 0; ks < 4; ++ks) {
        // B fragments (hi, lo) for 4 col-frags
        bf16x8 bh[4], bl[4];
        #pragma unroll
        for (int cf = 0; cf < 4; ++cf) {
            const int n     = wc + cf * 16 + l15;
            const int slotp = (ks * 4 + lg) ^ (n & 7);
            const int off   = n * 128 + slotp * 8;
            bh[cf] = *reinterpret_cast<const bf16x8*>(&Wsh[off]);
            bl[cf] = *reinterpret_cast<const bf16x8*>(&Wsh[16384 + off]);
        }
        // A fragments: transpose-read 8 f32 + split
        bf16x8 ah[2], al[2];
        #pragma unroll
        for (int rf = 0; rf < 2; ++rf) {
            const int row   = wr + rf * 16 + l15;
            const int s_loc = row >> 3;
            const int d     = row & 7;
            const int kb    = ks * 32 + lg * 8;
            const int xr    = (lg & 3) << 5;
            const char* zb  = reinterpret_cast<const char*>(zsh) + s_loc * 4096;
            bf16x8 h8, L8;
            #pragma unroll
            for (int j = 0; j < 8; ++j) {
                const float a = *reinterpret_cast<const float*>(
                    zb + ((32 * (kb + j) + 4 * d) ^ xr));
                const unsigned short hi = f32_to_bf16_rn(a);
                h8[j] = (short)hi;
                L8[j] = (short)f32_to_bf16_rn(a - bf16_bits_to_f32(hi));
            }
            ah[rf] = h8; al[rf] = L8;
        }
        #pragma unroll
        for (int rf = 0; rf < 2; ++rf)
            #pragma unroll
            for (int cf = 0; cf < 4; ++cf) {
                acc[rf][cf] = __builtin_amdgcn_mfma_f32_16x16x32_bf16(
                    ah[rf], bh[cf], acc[rf][cf], 0, 0, 0);
                acc[rf][cf] = __builtin_amdgcn_mfma_f32_16x16x32_bf16(
                    ah[rf], bl[cf], acc[rf][cf], 0, 0, 0);
                acc[rf][cf] = __builtin_amdgcn_mfma_f32_16x16x32_bf16(
                    al[rf], bh[cf], acc[rf][cf], 0, 0, 0);
            }
    }

    // ---- fused top-2 argmin epilogue (f64 compare) ----
    #pragma unroll
    for (int rf = 0; rf < 2; ++rf)
        #pragma unroll
        for (int j = 0; j < 4; ++j) {
            double v1 = 1e300, v2 = 1e300; int i1 = 0;
            #pragma unroll
            for (int cf = 0; cf < 4; ++cf) {           // ascending n: ties->low idx
                const int n = wc + cf * 16 + l15;
                const double v = wn_sh[n] - 2.0 * (double)acc[rf][cf][j];
                if (v < v1)      { v2 = v1; v1 = v; i1 = n; }
                else if (v < v2) { v2 = v; }
            }
            #pragma unroll
            for (int off = 1; off < 16; off <<= 1) {   // within 16-lane group
                const double ov1 = __shfl_xor(v1, off);
                const int    oi1 = __shfl_xor(i1, off);
                const double ov2 = __shfl_xor(v2, off);
                if (ov1 < v1 || (ov1 == v1 && oi1 < i1)) {
                    v2 = fmin(v1, ov2); v1 = ov1; i1 = oi1;
                } else {
                    v2 = fmin(v2, ov1);
                }
            }
            if (l15 == 0) {
                const int r = wr + rf * 16 + lg * 4 + j;
                cmb_v1[r][w_id & 1] = v1;
                cmb_v2[r][w_id & 1] = v2;
                cmb_i [r][w_id & 1] = i1;
            }
        }
    __syncthreads();

    if (tid < 128) {   // merge col-halves; half 0 has lower n -> wins ties
        const double v1a = cmb_v1[tid][0], v1b = cmb_v1[tid][1];
        double v1, v2; int i1;
        if (v1b < v1a) { v1 = v1b; i1 = cmb_i[tid][1]; v2 = fmin(v1a, cmb_v2[tid][1]); }
        else           { v1 = v1a; i1 = cmb_i[tid][0]; v2 = fmin(v1b, cmb_v2[tid][0]); }
        idx_sh[tid] = i1;
        if (v2 - v1 < GAP_T) sflag[tid >> 3] = 1;
    }
    __syncthreads();
    if (tid < 16 && sflag[tid]) {
        const int p = atomicAdd(flag_cnt, 1);
        flag_ids[p] = b0 + tid;
    }

    // ---- z_q gather-write: exact f32 = hi + lo (Sterbenz) ----
    for (int t = tid; t < 16384; t += 512) {
        const int s = t >> 10, i = t & 1023;
        const int k = i >> 3, d = i & 7;
        const int n = idx_sh[(s << 3) | d];
        const int off = n * 128 + (((k >> 3) ^ (n & 7)) << 3) + (k & 7);
        const float val = bf16_bits_to_f32((unsigned short)Wsh[off]) +
                          bf16_bits_to_f32((unsigned short)Wsh[16384 + off]);
        zq[(size_t)(b0 + s) * 1024 + i] = val;
    }
}

// ===================== exact f64 fixup (unchanged, round 4) =================
__global__ __launch_bounds__(512) void vq_fixup(
    const float* __restrict__ x,  const float* __restrict__ W1,
    const float* __restrict__ b1, const float* __restrict__ W2,
    const float* __restrict__ b2, const float* __restrict__ Wemb,
    const int* __restrict__ flag_cnt, const int* __restrict__ flag_ids,
    float* __restrict__ zq_out)
{
    __shared__ char smem[65536];
    float*  xsh  = reinterpret_cast<float*>(smem);
    double* h1sh = reinterpret_cast<double*>(smem + 49152);
    double* zsh  = reinterpret_cast<double*>(smem);
    double* dist = reinterpret_cast<double*>(smem + 32768);
    __shared__ int idxf[4][8];

    const int tid  = threadIdx.x;
    const int lane = tid & 63;
    const int wv   = tid >> 6;
    const int cnt  = *flag_cnt;

    for (int base = blockIdx.x * 4; base < cnt; base += gridDim.x * 4) {
        const int ns = min(4, cnt - base);
        __syncthreads();
        for (int i = tid; i < ns * 768; i += 512) {
            const int s = i / 768, k4 = i - s * 768;
            reinterpret_cast<float4*>(xsh)[s * 768 + k4] =
                reinterpret_cast<const float4*>(
                    &x[(size_t)flag_ids[base + s] * 3072])[k4];
        }
        __syncthreads();
        for (int j = tid; j < 400; j += 512) {
            double acc[4];
            #pragma unroll
            for (int s = 0; s < 4; ++s) acc[s] = (double)b1[j];
            const float4* wr = reinterpret_cast<const float4*>(&W1[(size_t)j * 3072]);
            for (int k4 = 0; k4 < 768; ++k4) {
                const float4 w = wr[k4];
                #pragma unroll
                for (int s = 0; s < 4; ++s) {
                    const float4 xv = reinterpret_cast<const float4*>(xsh)[s * 768 + k4];
                    acc[s] = fma((double)xv.x, (double)w.x, acc[s]);
                    acc[s] = fma((double)xv.y, (double)w.y, acc[s]);
                    acc[s] = fma((double)xv.z, (double)w.z, acc[s]);
                    acc[s] = fma((double)xv.w, (double)w.w, acc[s]);
                }
            }
            #pragma unroll
            for (int s = 0; s < 4; ++s)
                if (s < ns) h1sh[s * 400 + j] = acc[s] > 0.0 ? acc[s] : 0.0;
        }
        __syncthreads();
        for (int zi = tid; zi < 1024; zi += 512) {
            double acc[4];
            #pragma unroll
            for (int s = 0; s < 4; ++s) acc[s] = (double)b2[zi];
            const float4* wr = reinterpret_cast<const float4*>(&W2[(size_t)zi * 400]);
            for (int j4 = 0; j4 < 100; ++j4) {
                const float4 w = wr[j4];
                #pragma unroll
                for (int s = 0; s < 4; ++s) {
                    const double* hp = &h1sh[s * 400 + j4 * 4];
                    acc[s] = fma(hp[0], (double)w.x, acc[s]);
                    acc[s] = fma(hp[1], (double)w.y, acc[s]);
                    acc[s] = fma(hp[2], (double)w.z, acc[s]);
                    acc[s] = fma(hp[3], (double)w.w, acc[s]);
                }
            }
            #pragma unroll
            for (int s = 0; s < 4; ++s)
                if (s < ns) zsh[s * 1024 + zi] = acc[s];
        }
        __syncthreads();
        for (int t = tid; t < ns * 1024; t += 512) {
            const int n = t & 127, d = (t >> 7) & 7, s = t >> 10;
            double acc = 0.0;
            for (int k = 0; k < 128; ++k) {
                const double diff = zsh[s * 1024 + k * 8 + d] - (double)Wemb[k * 128 + n];
                acc = fma(diff, diff, acc);
            }
            dist[(s * 8 + d) * 128 + n] = acc;
        }
        __syncthreads();
        for (int p = wv; p < ns * 8; p += 8) {
            const double* dp = &dist[p * 128];
            double v0 = dp[lane], vx = dp[lane + 64];
            double v; int ix;
            if (vx < v0) { v = vx; ix = lane + 64; }
            else         { v = v0; ix = lane; }
            for (int off = 32; off > 0; off >>= 1) {
                const double ov = __shfl_down(v, off);
                const int    oi = __shfl_down(ix, off);
                if (ov < v || (ov == v && oi < ix)) { v = ov; ix = oi; }
            }
            if (lane == 0) idxf[p >> 3][p & 7] = ix;
        }
        __syncthreads();
        for (int i = tid; i < ns * 1024; i += 512) {
            const int s = i >> 10, zi = i & 1023;
            zq_out[(size_t)flag_ids[base + s] * 1024 + zi] =
                Wemb[(zi >> 3) * 128 + idxf[s][zi & 7]];
        }
    }
}

// ---------------------------------------------------------------------------
extern "C" void kernel_launch(void* const* d_in, const int* in_sizes, int n_in,
                              void* d_out, int out_size, void* d_ws, size_t ws_size,
                              hipStream_t stream)
{
    const float* x    = (const float*)d_in[0];
    const float* W1   = (const float*)d_in[1];
    const float* b1   = (const float*)d_in[2];
    const float* W2   = (const float*)d_in[3];
    const float* b2   = (const float*)d_in[4];
    const float* W3   = (const float*)d_in[5];
    const float* b3   = (const float*)d_in[6];
    const float* W4   = (const float*)d_in[7];
    const float* b4   = (const float*)d_in[8];
    const float* Wemb = (const float*)d_in[9];

    const int B = 16384;
    float* out   = (float*)d_out;
    float* recon = out;                                // B*3072
    float* z_e   = out + (size_t)B * 3072;             // B*1024
    float* emb_o = z_e + (size_t)B * 1024;             // B*1024 == z_q

    float*  h        = (float*)d_ws;                               // B*400
    int*    flag_cnt = (int*)((char*)d_ws + (28ull << 20));        // @28MB
    int*    flag_ids = flag_cnt + 64;                              // 64KB worth
    short*  planes   = (short*)((char*)d_ws + (29ull << 20));      // 64KB
    double* wn       = (double*)((char*)d_ws + (29ull << 20) + 65536);

    const dim3 blk(256);

    vq_prep<<<dim3(1), blk, 0, stream>>>(Wemb, planes, wn, flag_cnt);

    // encoder: bf16x2-split MFMA
    gemm_bf16s<2, 1><<<dim3(4, 128), blk, 0, stream>>>(x, W1, b1, h,   B, 400,  3072);
    gemm_bf16s<2, 0><<<dim3(8, 128), blk, 0, stream>>>(h, W2, b2, z_e, B, 1024, 400);

    // VQ: MFMA dots + fused top-2 argmin + gap flagging, then exact fixup
    vq_mfma<<<dim3(1024), dim3(512), 0, stream>>>(z_e, planes, wn, emb_o,
                                                  flag_cnt, flag_ids);
    vq_fixup<<<dim3(512), dim3(512), 0, stream>>>(x, W1, b1, W2, b2, Wemb,
                                                  flag_cnt, flag_ids, emb_o);

    // decoder: plain bf16 MFMA
    gemm_bf16s<1, 1><<<dim3(4, 128),  blk, 0, stream>>>(emb_o, W3, b3, h,     B, 400,  1024);
    gemm_bf16s<1, 2><<<dim3(24, 128), blk, 0, stream>>>(h,     W4, b4, recon, B, 3072, 400);
}

// Round 6
// 895.184 us; speedup vs baseline: 2.6346x; 1.1833x over previous
//
#include <hip/hip_runtime.h>
#include <math.h>

// ---------------------------------------------------------------------------
// VQ-VAE forward on MI355X — round 6: pre-split bf16 operand planes.
//   All GEMM operands stored as tiled, pre-swizzled bf16 planes whose memory
//   order == the LDS tile layout -> staging is a linear 8KB global_load_lds
//   copy, K-loops contain zero conversion VALU. Numerics bit-identical to
//   round 5 (same rn/residual splits, same MFMA order).
//   g1: h1 = relu(x @ W1^T + b1)        [x,W1 hi/lo planes -> h1 hi/lo planes]
//   g2: z_e = h1 @ W2^T + b2            [planes -> f32 z_e output]
//   vq: MFMA dots + top-2 argmin + gap flag -> exact f64 fixup
//   g3: h3 = relu(z_q @ W3^T + b3)      [A from f32 z_q (convert), B plane]
//   g4: recon = sigmoid(h3 @ W4^T + b4) [planes -> f32 recon]
// Placement: x planes in recon section (dead till g4), h1 planes in emb_o
// section (dead till vq), everything else in ws (~25.4 MB).
// ---------------------------------------------------------------------------

typedef short bf16x8 __attribute__((ext_vector_type(8)));
typedef short short8 __attribute__((ext_vector_type(8)));
typedef float f32x4  __attribute__((ext_vector_type(4)));

#define GAP_T 2e-4

__device__ __forceinline__ unsigned short f32_to_bf16_rn(float v) {
    union { float f; unsigned u; } c; c.f = v;
    unsigned r = c.u + 0x7FFFu + ((c.u >> 16) & 1u);
    return (unsigned short)(r >> 16);
}
__device__ __forceinline__ float bf16_bits_to_f32(unsigned short b) {
    union { unsigned u; float f; } c; c.u = ((unsigned)b) << 16;
    return c.f;
}
__device__ __forceinline__ void glds16(const short* g, short* l) {
    __builtin_amdgcn_global_load_lds(
        (const __attribute__((address_space(1))) unsigned int*)g,
        (__attribute__((address_space(3))) unsigned int*)l, 16, 0, 0);
}

// Tile layout (one 128x32 tile = 4096 shorts = 8KB):
//   pos = row*32 + ((slot ^ (row&3))<<3) + (k&7),  slot = (k>>3)&3
// == the LDS layout the fragment reader uses (2-way bank aliasing, free).

// ===================== plane prep: weights (B operand) ======================
// grid = NB*KT blocks; rows (N dim) zero-padded to NB*128, cols to KT*32.
__global__ __launch_bounds__(256) void prep_wplanes(
    const float* __restrict__ Wsrc, int N, int K, int KT,
    short* __restrict__ hi, short* __restrict__ lo)
{
    const int kt = blockIdx.x % KT;
    const int nb = blockIdx.x / KT;
    const size_t tb = (size_t)blockIdx.x * 4096;
    for (int ci = threadIdx.x; ci < 512; ci += 256) {
        const int row = ci >> 2;
        const int sl  = ci & 3;
        const int k0  = ((sl ^ (row & 3)) << 3);
        const int n   = nb * 128 + row;
        const int kk  = kt * 32 + k0;
        float f[8];
        #pragma unroll
        for (int e = 0; e < 8; ++e)
            f[e] = (n < N && kk + e < K) ? Wsrc[(size_t)n * K + kk + e] : 0.f;
        short8 h, l;
        #pragma unroll
        for (int e = 0; e < 8; ++e) {
            const unsigned short hb = f32_to_bf16_rn(f[e]);
            h[e] = (short)hb;
            l[e] = (short)f32_to_bf16_rn(f[e] - bf16_bits_to_f32(hb));
        }
        *reinterpret_cast<short8*>(&hi[tb + ci * 8]) = h;
        if (lo) *reinterpret_cast<short8*>(&lo[tb + ci * 8]) = l;
    }
}

// ========================= plane prep: x (A operand) ========================
// grid = 128*96 = 12288 blocks (full tiles, no guards).
__global__ __launch_bounds__(256) void prep_xplanes(
    const float* __restrict__ x, short* __restrict__ hi, short* __restrict__ lo)
{
    const int kt = blockIdx.x % 96;
    const int mb = blockIdx.x / 96;
    const size_t tb = (size_t)blockIdx.x * 4096;
    for (int ci = threadIdx.x; ci < 512; ci += 256) {
        const int row = ci >> 2;
        const int sl  = ci & 3;
        const int k0  = ((sl ^ (row & 3)) << 3);
        const float* src = &x[(size_t)(mb * 128 + row) * 3072 + kt * 32 + k0];
        const float4 f0 = *reinterpret_cast<const float4*>(src);
        const float4 f1 = *reinterpret_cast<const float4*>(src + 4);
        const float ff[8] = {f0.x, f0.y, f0.z, f0.w, f1.x, f1.y, f1.z, f1.w};
        short8 h, l;
        #pragma unroll
        for (int e = 0; e < 8; ++e) {
            const unsigned short hb = f32_to_bf16_rn(ff[e]);
            h[e] = (short)hb;
            l[e] = (short)f32_to_bf16_rn(ff[e] - bf16_bits_to_f32(hb));
        }
        *reinterpret_cast<short8*>(&hi[tb + ci * 8]) = h;
        *reinterpret_cast<short8*>(&lo[tb + ci * 8]) = l;
    }
}

// ====================== plane-fed MFMA GEMM (NT) ===========================
// AMODE: 0 = A from planes (glds), 1 = A from f32 row-major (convert hi only)
// OUTMODE: 0 = f32 C; 1 = hi plane; 2 = hi+lo planes
template<int NSPLIT, int ACT, int AMODE, int OUTMODE>
__global__ __launch_bounds__(256) void gemm_pl(
    const short* __restrict__ Ahi, const short* __restrict__ Alo,
    const float* __restrict__ Af32, int AK,
    const short* __restrict__ Bhi, const short* __restrict__ Blo,
    const float* __restrict__ bias,
    float* __restrict__ Cf32, short* __restrict__ Cphi, short* __restrict__ Cplo,
    int N, int KT, int KTout)
{
    __shared__ short lds[NSPLIT * 2 * 4096];   // A splits then B splits

    const int tid  = threadIdx.x;
    const int lane = tid & 63;
    const int w_id = tid >> 6;
    const int wr   = (w_id >> 1) * 64;
    const int wc   = (w_id & 1)  * 64;
    const int m0   = blockIdx.y * 128;
    const int n0   = blockIdx.x * 128;
    const int l15  = lane & 15;
    const int lg   = lane >> 4;

    f32x4 acc[4][4];
    #pragma unroll
    for (int i = 0; i < 4; ++i)
        #pragma unroll
        for (int j = 0; j < 4; ++j) acc[i][j] = (f32x4){0.f, 0.f, 0.f, 0.f};

    for (int kt = 0; kt < KT; ++kt) {
        // ---- stage A ----
        if (AMODE == 0) {
            const size_t at = ((size_t)blockIdx.y * KT + kt) * 4096;
            #pragma unroll
            for (int q = 0; q < 2; ++q) {
                const int o = (w_id * 2 + q) * 512 + lane * 8;
                glds16(Ahi + at + o, &lds[o]);
                if (NSPLIT > 1) glds16(Alo + at + o, &lds[4096 + o]);
            }
        } else {
            #pragma unroll
            for (int i = 0; i < 2; ++i) {
                const int ci  = tid + i * 256;
                const int row = ci >> 2;
                const int sl  = ci & 3;
                const int k0  = ((sl ^ (row & 3)) << 3);
                const float* src = &Af32[(size_t)(m0 + row) * AK + kt * 32 + k0];
                const float4 f0 = *reinterpret_cast<const float4*>(src);
                const float4 f1 = *reinterpret_cast<const float4*>(src + 4);
                const float ff[8] = {f0.x, f0.y, f0.z, f0.w, f1.x, f1.y, f1.z, f1.w};
                short8 h;
                #pragma unroll
                for (int e = 0; e < 8; ++e) h[e] = (short)f32_to_bf16_rn(ff[e]);
                *reinterpret_cast<short8*>(&lds[ci * 8]) = h;
            }
        }
        // ---- stage B (always planes) ----
        {
            const size_t bt = ((size_t)blockIdx.x * KT + kt) * 4096;
            #pragma unroll
            for (int q = 0; q < 2; ++q) {
                const int o = (w_id * 2 + q) * 512 + lane * 8;
                glds16(Bhi + bt + o, &lds[NSPLIT * 4096 + o]);
                if (NSPLIT > 1) glds16(Blo + bt + o, &lds[(NSPLIT + 1) * 4096 + o]);
            }
        }
        __syncthreads();

        // ---- fragments + MFMA (layout identical to round 5) ----
        bf16x8 bfr[4][NSPLIT];
        #pragma unroll
        for (int fc = 0; fc < 4; ++fc) {
            const int rn  = wc + fc * 16 + l15;
            const int idx = rn * 32 + ((lg ^ (rn & 3)) << 3);
            #pragma unroll
            for (int s = 0; s < NSPLIT; ++s)
                bfr[fc][s] = *reinterpret_cast<const bf16x8*>(&lds[(NSPLIT + s) * 4096 + idx]);
        }
        #pragma unroll
        for (int fr = 0; fr < 4; ++fr) {
            const int rm  = wr + fr * 16 + l15;
            const int idx = rm * 32 + ((lg ^ (rm & 3)) << 3);
            const bf16x8 a0 = *reinterpret_cast<const bf16x8*>(&lds[idx]);
            bf16x8 a1;
            if (NSPLIT > 1)
                a1 = *reinterpret_cast<const bf16x8*>(&lds[4096 + idx]);
            #pragma unroll
            for (int fc = 0; fc < 4; ++fc) {
                acc[fr][fc] = __builtin_amdgcn_mfma_f32_16x16x32_bf16(
                    a0, bfr[fc][0], acc[fr][fc], 0, 0, 0);
                if (NSPLIT > 1) {
                    acc[fr][fc] = __builtin_amdgcn_mfma_f32_16x16x32_bf16(
                        a0, bfr[fc][1], acc[fr][fc], 0, 0, 0);
                    acc[fr][fc] = __builtin_amdgcn_mfma_f32_16x16x32_bf16(
                        a1, bfr[fc][0], acc[fr][fc], 0, 0, 0);
                }
            }
        }
        __syncthreads();
    }

    // ---- epilogue ----
    float bv[4];
    #pragma unroll
    for (int fc = 0; fc < 4; ++fc) {
        const int col = n0 + wc + fc * 16 + l15;
        bv[fc] = (col < N) ? bias[col] : 0.f;
    }
    #pragma unroll
    for (int fr = 0; fr < 4; ++fr) {
        #pragma unroll
        for (int fc = 0; fc < 4; ++fc) {
            const int col = n0 + wc + fc * 16 + l15;
            #pragma unroll
            for (int j = 0; j < 4; ++j) {
                const int rowg = m0 + wr + fr * 16 + lg * 4 + j;
                float v = acc[fr][fc][j] + bv[fc];
                if (ACT == 1) v = fmaxf(v, 0.f);
                else if (ACT == 2) v = 1.f / (1.f + expf(-v));
                if (OUTMODE == 0) {
                    if (col < N) Cf32[(size_t)rowg * N + col] = v;
                } else {
                    const int kto = col >> 5;
                    if (kto < KTout) {
                        const int r = rowg & 127, k = col & 31;
                        const size_t off = ((size_t)blockIdx.y * KTout + kto) * 4096
                                         + r * 32 + (((k >> 3) ^ (r & 3)) << 3) + (k & 7);
                        const unsigned short hb = f32_to_bf16_rn(v);
                        Cphi[off] = (short)hb;
                        if (OUTMODE == 2)
                            Cplo[off] = (short)f32_to_bf16_rn(v - bf16_bits_to_f32(hb));
                    }
                }
            }
        }
    }
}

// ============================ VQ prep (one block) ===========================
__global__ void vq_prep(const float* __restrict__ Wemb, short* __restrict__ planes,
                        double* __restrict__ wn, int* __restrict__ flag_cnt)
{
    const int tid = threadIdx.x;
    if (tid == 0) *flag_cnt = 0;
    if (tid < 128) {
        double s = 0.0;
        for (int k = 0; k < 128; ++k) {
            const double w = (double)Wemb[k * 128 + tid];
            s = fma(w, w, s);
        }
        wn[tid] = s;
    }
    for (int t = tid; t < 16384; t += 256) {
        const int k = t >> 7, n = t & 127;
        const float w = Wemb[t];
        const unsigned short hi = f32_to_bf16_rn(w);
        const unsigned short lo = f32_to_bf16_rn(w - bf16_bits_to_f32(hi));
        const int off = n * 128 + (((k >> 3) ^ (n & 7)) << 3) + (k & 7);
        planes[off]         = (short)hi;
        planes[16384 + off] = (short)lo;
    }
}

// ============================ VQ MFMA + argmin ==============================
// (unchanged from round 5 — known good)
__global__ __launch_bounds__(512) void vq_mfma(
    const float* __restrict__ z_e, const short* __restrict__ planes,
    const double* __restrict__ wn_g, float* __restrict__ zq,
    int* __restrict__ flag_cnt, int* __restrict__ flag_ids)
{
    __shared__ short  Wsh[32768];
    __shared__ float  zsh[16 * 1024];
    __shared__ double wn_sh[128];
    __shared__ double cmb_v1[128][2];
    __shared__ double cmb_v2[128][2];
    __shared__ int    cmb_i[128][2];
    __shared__ int    idx_sh[128];
    __shared__ int    sflag[16];

    const int tid = threadIdx.x;
    const int b0  = blockIdx.x * 16;

    for (int c = tid; c < 4096; c += 512)
        *reinterpret_cast<int4*>(&Wsh[c * 8]) =
            *reinterpret_cast<const int4*>(&planes[c * 8]);
    for (int c = tid; c < 128; c += 512) wn_sh[c] = wn_g[c];
    for (int c = tid; c < 4096; c += 512) {
        const int D    = c * 16;
        const int s    = D >> 12;
        const int dr   = D & 4095;
        const int srcb = dr ^ (((dr >> 8) & 3) << 5);
        *reinterpret_cast<int4*>(reinterpret_cast<char*>(zsh) + D) =
            *reinterpret_cast<const int4*>(
                reinterpret_cast<const char*>(z_e) + (size_t)(b0 + s) * 4096 + srcb);
    }
    if (tid < 16) sflag[tid] = 0;
    __syncthreads();

    const int lane = tid & 63;
    const int w_id = tid >> 6;
    const int wr   = (w_id >> 1) * 32;
    const int wc   = (w_id & 1) * 64;
    const int l15  = lane & 15;
    const int lg   = lane >> 4;

    f32x4 acc[2][4];
    #pragma unroll
    for (int i = 0; i < 2; ++i)
        #pragma unroll
        for (int j = 0; j < 4; ++j) acc[i][j] = (f32x4){0.f, 0.f, 0.f, 0.f};

    #pragma unroll
    for (int ks = 0; ks < 4; ++ks) {
        bf16x8 bh[4], bl[4];
        #pragma unroll
        for (int cf = 0; cf < 4; ++cf) {
            const int n     = wc + cf * 16 + l15;
            const int slotp = (ks * 4 + lg) ^ (n & 7);
            const int off   = n * 128 + slotp * 8;
            bh[cf] = *reinterpret_cast<const bf16x8*>(&Wsh[off]);
            bl[cf] = *reinterpret_cast<const bf16x8*>(&Wsh[16384 + off]);
        }
        bf16x8 ah[2], al[2];
        #pragma unroll
        for (int rf = 0; rf < 2; ++rf) {
            const int row   = wr + rf * 16 + l15;
            const int s_loc = row >> 3;
            const int d     = row & 7;
            const int kb    = ks * 32 + lg * 8;
            const int xr    = (lg & 3) << 5;
            const char* zb  = reinterpret_cast<const char*>(zsh) + s_loc * 4096;
            bf16x8 h8, L8;
            #pragma unroll
            for (int j = 0; j < 8; ++j) {
                const float a = *reinterpret_cast<const float*>(
                    zb + ((32 * (kb + j) + 4 * d) ^ xr));
                const unsigned short hi = f32_to_bf16_rn(a);
                h8[j] = (short)hi;
                L8[j] = (short)f32_to_bf16_rn(a - bf16_bits_to_f32(hi));
            }
            ah[rf] = h8; al[rf] = L8;
        }
        #pragma unroll
        for (int rf = 0; rf < 2; ++rf)
            #pragma unroll
            for (int cf = 0; cf < 4; ++cf) {
                acc[rf][cf] = __builtin_amdgcn_mfma_f32_16x16x32_bf16(
                    ah[rf], bh[cf], acc[rf][cf], 0, 0, 0);
                acc[rf][cf] = __builtin_amdgcn_mfma_f32_16x16x32_bf16(
                    ah[rf], bl[cf], acc[rf][cf], 0, 0, 0);
                acc[rf][cf] = __builtin_amdgcn_mfma_f32_16x16x32_bf16(
                    al[rf], bh[cf], acc[rf][cf], 0, 0, 0);
            }
    }

    #pragma unroll
    for (int rf = 0; rf < 2; ++rf)
        #pragma unroll
        for (int j = 0; j < 4; ++j) {
            double v1 = 1e300, v2 = 1e300; int i1 = 0;
            #pragma unroll
            for (int cf = 0; cf < 4; ++cf) {
                const int n = wc + cf * 16 + l15;
                const double v = wn_sh[n] - 2.0 * (double)acc[rf][cf][j];
                if (v < v1)      { v2 = v1; v1 = v; i1 = n; }
                else if (v < v2) { v2 = v; }
            }
            #pragma unroll
            for (int off = 1; off < 16; off <<= 1) {
                const double ov1 = __shfl_xor(v1, off);
                const int    oi1 = __shfl_xor(i1, off);
                const double ov2 = __shfl_xor(v2, off);
                if (ov1 < v1 || (ov1 == v1 && oi1 < i1)) {
                    v2 = fmin(v1, ov2); v1 = ov1; i1 = oi1;
                } else {
                    v2 = fmin(v2, ov1);
                }
            }
            if (l15 == 0) {
                const int r = wr + rf * 16 + lg * 4 + j;
                cmb_v1[r][w_id & 1] = v1;
                cmb_v2[r][w_id & 1] = v2;
                cmb_i [r][w_id & 1] = i1;
            }
        }
    __syncthreads();

    if (tid < 128) {
        const double v1a = cmb_v1[tid][0], v1b = cmb_v1[tid][1];
        double v1, v2; int i1;
        if (v1b < v1a) { v1 = v1b; i1 = cmb_i[tid][1]; v2 = fmin(v1a, cmb_v2[tid][1]); }
        else           { v1 = v1a; i1 = cmb_i[tid][0]; v2 = fmin(v1b, cmb_v2[tid][0]); }
        idx_sh[tid] = i1;
        if (v2 - v1 < GAP_T) sflag[tid >> 3] = 1;
    }
    __syncthreads();
    if (tid < 16 && sflag[tid]) {
        const int p = atomicAdd(flag_cnt, 1);
        flag_ids[p] = b0 + tid;
    }

    for (int t = tid; t < 16384; t += 512) {
        const int s = t >> 10, i = t & 1023;
        const int k = i >> 3, d = i & 7;
        const int n = idx_sh[(s << 3) | d];
        const int off = n * 128 + (((k >> 3) ^ (n & 7)) << 3) + (k & 7);
        const float val = bf16_bits_to_f32((unsigned short)Wsh[off]) +
                          bf16_bits_to_f32((unsigned short)Wsh[16384 + off]);
        zq[(size_t)(b0 + s) * 1024 + i] = val;
    }
}

// ===================== exact f64 fixup (unchanged) ==========================
__global__ __launch_bounds__(512) void vq_fixup(
    const float* __restrict__ x,  const float* __restrict__ W1,
    const float* __restrict__ b1, const float* __restrict__ W2,
    const float* __restrict__ b2, const float* __restrict__ Wemb,
    const int* __restrict__ flag_cnt, const int* __restrict__ flag_ids,
    float* __restrict__ zq_out)
{
    __shared__ char smem[65536];
    float*  xsh  = reinterpret_cast<float*>(smem);
    double* h1sh = reinterpret_cast<double*>(smem + 49152);
    double* zsh  = reinterpret_cast<double*>(smem);
    double* dist = reinterpret_cast<double*>(smem + 32768);
    __shared__ int idxf[4][8];

    const int tid  = threadIdx.x;
    const int lane = tid & 63;
    const int wv   = tid >> 6;
    const int cnt  = *flag_cnt;

    for (int base = blockIdx.x * 4; base < cnt; base += gridDim.x * 4) {
        const int ns = min(4, cnt - base);
        __syncthreads();
        for (int i = tid; i < ns * 768; i += 512) {
            const int s = i / 768, k4 = i - s * 768;
            reinterpret_cast<float4*>(xsh)[s * 768 + k4] =
                reinterpret_cast<const float4*>(
                    &x[(size_t)flag_ids[base + s] * 3072])[k4];
        }
        __syncthreads();
        for (int j = tid; j < 400; j += 512) {
            double acc[4];
            #pragma unroll
            for (int s = 0; s < 4; ++s) acc[s] = (double)b1[j];
            const float4* wr = reinterpret_cast<const float4*>(&W1[(size_t)j * 3072]);
            for (int k4 = 0; k4 < 768; ++k4) {
                const float4 w = wr[k4];
                #pragma unroll
                for (int s = 0; s < 4; ++s) {
                    const float4 xv = reinterpret_cast<const float4*>(xsh)[s * 768 + k4];
                    acc[s] = fma((double)xv.x, (double)w.x, acc[s]);
                    acc[s] = fma((double)xv.y, (double)w.y, acc[s]);
                    acc[s] = fma((double)xv.z, (double)w.z, acc[s]);
                    acc[s] = fma((double)xv.w, (double)w.w, acc[s]);
                }
            }
            #pragma unroll
            for (int s = 0; s < 4; ++s)
                if (s < ns) h1sh[s * 400 + j] = acc[s] > 0.0 ? acc[s] : 0.0;
        }
        __syncthreads();
        for (int zi = tid; zi < 1024; zi += 512) {
            double acc[4];
            #pragma unroll
            for (int s = 0; s < 4; ++s) acc[s] = (double)b2[zi];
            const float4* wr = reinterpret_cast<const float4*>(&W2[(size_t)zi * 400]);
            for (int j4 = 0; j4 < 100; ++j4) {
                const float4 w = wr[j4];
                #pragma unroll
                for (int s = 0; s < 4; ++s) {
                    const double* hp = &h1sh[s * 400 + j4 * 4];
                    acc[s] = fma(hp[0], (double)w.x, acc[s]);
                    acc[s] = fma(hp[1], (double)w.y, acc[s]);
                    acc[s] = fma(hp[2], (double)w.z, acc[s]);
                    acc[s] = fma(hp[3], (double)w.w, acc[s]);
                }
            }
            #pragma unroll
            for (int s = 0; s < 4; ++s)
                if (s < ns) zsh[s * 1024 + zi] = acc[s];
        }
        __syncthreads();
        for (int t = tid; t < ns * 1024; t += 512) {
            const int n = t & 127, d = (t >> 7) & 7, s = t >> 10;
            double acc = 0.0;
            for (int k = 0; k < 128; ++k) {
                const double diff = zsh[s * 1024 + k * 8 + d] - (double)Wemb[k * 128 + n];
                acc = fma(diff, diff, acc);
            }
            dist[(s * 8 + d) * 128 + n] = acc;
        }
        __syncthreads();
        for (int p = wv; p < ns * 8; p += 8) {
            const double* dp = &dist[p * 128];
            double v0 = dp[lane], vx = dp[lane + 64];
            double v; int ix;
            if (vx < v0) { v = vx; ix = lane + 64; }
            else         { v = v0; ix = lane; }
            for (int off = 32; off > 0; off >>= 1) {
                const double ov = __shfl_down(v, off);
                const int    oi = __shfl_down(ix, off);
                if (ov < v || (ov == v && oi < ix)) { v = ov; ix = oi; }
            }
            if (lane == 0) idxf[p >> 3][p & 7] = ix;
        }
        __syncthreads();
        for (int i = tid; i < ns * 1024; i += 512) {
            const int s = i >> 10, zi = i & 1023;
            zq_out[(size_t)flag_ids[base + s] * 1024 + zi] =
                Wemb[(zi >> 3) * 128 + idxf[s][zi & 7]];
        }
    }
}

// ---------------------------------------------------------------------------
extern "C" void kernel_launch(void* const* d_in, const int* in_sizes, int n_in,
                              void* d_out, int out_size, void* d_ws, size_t ws_size,
                              hipStream_t stream)
{
    const float* x    = (const float*)d_in[0];
    const float* W1   = (const float*)d_in[1];
    const float* b1   = (const float*)d_in[2];
    const float* W2   = (const float*)d_in[3];
    const float* b2   = (const float*)d_in[4];
    const float* W3   = (const float*)d_in[5];
    const float* b3   = (const float*)d_in[6];
    const float* W4   = (const float*)d_in[7];
    const float* b4   = (const float*)d_in[8];
    const float* Wemb = (const float*)d_in[9];

    const int B = 16384;
    float* out   = (float*)d_out;
    float* recon = out;                                // B*3072
    float* z_e   = out + (size_t)B * 3072;             // B*1024
    float* emb_o = z_e + (size_t)B * 1024;             // B*1024 == z_q

    // plane sizes (shorts)
    constexpr size_t X_PL  = 50331648;  // 128*96*4096
    constexpr size_t H1_PL = 6815744;   // 128*13*4096
    constexpr size_t H3_PL = 6815744;
    constexpr size_t W1_PL = 1572864;   // 4*96*4096
    constexpr size_t W2_PL = 425984;    // 8*13*4096
    constexpr size_t W3_PL = 524288;    // 4*32*4096
    constexpr size_t W4_PL = 1277952;   // 24*13*4096

    // x planes in recon section (dead until g4); h1 planes in emb_o (dead
    // until vq_mfma overwrites with z_q)
    short* xh  = (short*)recon;
    short* xl  = xh + X_PL;
    short* h1h = (short*)emb_o;
    short* h1l = h1h + H1_PL;

    // ws layout (~25.4 MB)
    short*  h3h      = (short*)d_ws;
    short*  w1h      = h3h + H3_PL;
    short*  w1l      = w1h + W1_PL;
    short*  w2h      = w1l + W1_PL;
    short*  w2l      = w2h + W2_PL;
    short*  w3h      = w2l + W2_PL;
    short*  w4h      = w3h + W3_PL;
    short*  wembpl   = w4h + W4_PL;                    // 32768 shorts
    double* wn       = (double*)(wembpl + 32768);      // 128 doubles
    int*    flag_cnt = (int*)(wn + 128);
    int*    flag_ids = flag_cnt + 64;

    // ---- prep: one-time splits into pre-swizzled tiled planes ----
    prep_wplanes<<<dim3(384), dim3(256), 0, stream>>>(W1, 400, 3072, 96, w1h, w1l);
    prep_wplanes<<<dim3(104), dim3(256), 0, stream>>>(W2, 1024, 400, 13, w2h, w2l);
    prep_wplanes<<<dim3(128), dim3(256), 0, stream>>>(W3, 400, 1024, 32, w3h, nullptr);
    prep_wplanes<<<dim3(312), dim3(256), 0, stream>>>(W4, 3072, 400, 13, w4h, nullptr);
    prep_xplanes<<<dim3(12288), dim3(256), 0, stream>>>(x, xh, xl);
    vq_prep<<<dim3(1), dim3(256), 0, stream>>>(Wemb, wembpl, wn, flag_cnt);

    // ---- encoder ----
    gemm_pl<2, 1, 0, 2><<<dim3(4, 128), dim3(256), 0, stream>>>(
        xh, xl, nullptr, 0, w1h, w1l, b1, nullptr, h1h, h1l, 400, 96, 13);
    gemm_pl<2, 0, 0, 0><<<dim3(8, 128), dim3(256), 0, stream>>>(
        h1h, h1l, nullptr, 0, w2h, w2l, b2, z_e, nullptr, nullptr, 1024, 13, 0);

    // ---- VQ + fixup ----
    vq_mfma<<<dim3(1024), dim3(512), 0, stream>>>(z_e, wembpl, wn, emb_o,
                                                  flag_cnt, flag_ids);
    vq_fixup<<<dim3(512), dim3(512), 0, stream>>>(x, W1, b1, W2, b2, Wemb,
                                                  flag_cnt, flag_ids, emb_o);

    // ---- decoder ----
    gemm_pl<1, 1, 1, 1><<<dim3(4, 128), dim3(256), 0, stream>>>(
        nullptr, nullptr, emb_o, 1024, w3h, nullptr, b3, nullptr, h3h, nullptr,
        400, 32, 13);
    gemm_pl<1, 2, 0, 0><<<dim3(24, 128), dim3(256), 0, stream>>>(
        h3h, nullptr, nullptr, 0, w4h, nullptr, b4, recon, nullptr, nullptr,
        3072, 13, 0);
}